// Round 11
// baseline (4887.139 us; speedup 1.0000x reference)
//
#include <hip/hip_runtime.h>
#include <cstdint>
#include <cstddef>

// Stage-A dense grid dims: flat cell = (z<<12)|(y<<5)|x
#define AD 128
#define AH 128
#define AW 32
#define NCELL (AD*AH*AW)   // 524288

// XCD-contiguous block swizzle: blocks with equal (bid&7) — same XCD under
// round-robin dispatch — get CONTIGUOUS logical ranges. Perf-only remap.
__device__ __forceinline__ int xcd_swizzle(int bx, int nb) {
    int xcd = bx & 7, slot = bx >> 3;
    int base = nb >> 3, rem = nb & 7;
    return (xcd < rem) ? (xcd*(base+1) + slot) : (rem + xcd*base + slot);
}

// ---------------- setup: grid + spatial sort (occupancy scan) ----------------
__global__ void build_grid_k(const int* __restrict__ coors, int* __restrict__ grid, int N) {
    int i = blockIdx.x * 256 + threadIdx.x;
    if (i >= N) return;
    int z = coors[i*4+1], y = coors[i*4+2], x = coors[i*4+3];
    grid[(z*AH + y)*AW + x] = i;
}

__global__ __launch_bounds__(256) void scan1_k(const int* __restrict__ grid, int* __restrict__ partial) {
    __shared__ int sm[256];
    int tid = threadIdx.x;
    int base = blockIdx.x*1024 + tid*4;
    int c = 0;
#pragma unroll
    for (int k = 0; k < 4; ++k) c += (grid[base+k] >= 0) ? 1 : 0;
    sm[tid] = c; __syncthreads();
    for (int off = 128; off; off >>= 1) {
        if (tid < off) sm[tid] += sm[tid+off];
        __syncthreads();
    }
    if (tid == 0) partial[blockIdx.x] = sm[0];
}

__global__ __launch_bounds__(512) void scan2_k(int* __restrict__ partial) {
    __shared__ int sm[512];
    int tid = threadIdx.x;
    int own = partial[tid];
    sm[tid] = own; __syncthreads();
    for (int off = 1; off < 512; off <<= 1) {
        int v = (tid >= off) ? sm[tid-off] : 0;
        __syncthreads();
        sm[tid] += v;
        __syncthreads();
    }
    partial[tid] = sm[tid] - own;   // exclusive
}

__global__ __launch_bounds__(256) void scan3_k(const int* __restrict__ grid, const int* __restrict__ partial,
                                               const float* __restrict__ features,
                                               int* __restrict__ grid2, int* __restrict__ cellOf,
                                               float* __restrict__ featS) {
    __shared__ int sm[256];
    int tid = threadIdx.x;
    int base = blockIdx.x*1024 + tid*4;
    int olds[4]; int c = 0;
#pragma unroll
    for (int k = 0; k < 4; ++k) { olds[k] = grid[base+k]; c += (olds[k] >= 0) ? 1 : 0; }
    int own = c;
    sm[tid] = c; __syncthreads();
    for (int off = 1; off < 256; off <<= 1) {
        int v = (tid >= off) ? sm[tid-off] : 0;
        __syncthreads();
        sm[tid] += v;
        __syncthreads();
    }
    int j = partial[blockIdx.x] + sm[tid] - own;
#pragma unroll
    for (int k = 0; k < 4; ++k) {
        int cell = base + k, old = olds[k];
        if (old >= 0) {
            grid2[cell] = j; cellOf[j] = cell;
            featS[j*4+0] = features[old*3+0];
            featS[j*4+1] = features[old*3+1];
            featS[j*4+2] = features[old*3+2];
            featS[j*4+3] = 0.f;
            ++j;
        } else grid2[cell] = -1;
    }
}

// ---------------- first layer: CI=3 (stride 4), CO=32 ----------------
__global__ __launch_bounds__(256)
void subm_first_k(const float* __restrict__ featS, const int* __restrict__ grid2,
                  const int* __restrict__ cellOf, const float* __restrict__ w,
                  float* __restrict__ out, int nsites)
{
    int j = blockIdx.x*256 + threadIdx.x;
    bool ok = j < nsites;
    int cell = ok ? cellOf[j] : 0;
    int z = cell >> 12, y = (cell >> 5) & 127, x = cell & 31;
    float acc[32];
#pragma unroll
    for (int n = 0; n < 32; ++n) acc[n] = 0.f;
    for (int t = 0; t < 27; ++t) {
        int nz = z + t/9 - 1, ny = y + (t/3)%3 - 1, nx = x + t%3 - 1;
        int s = -1;
        if (ok && nz>=0 && nz<AD && ny>=0 && ny<AH && nx>=0 && nx<AW)
            s = grid2[(nz<<12)|(ny<<5)|nx];
        float4 v = make_float4(0.f,0.f,0.f,0.f);
        if (s >= 0) v = ((const float4*)featS)[s];
        const float* wc = w + t*3*32;
        float av[3] = {v.x, v.y, v.z};
#pragma unroll
        for (int u = 0; u < 3; ++u)
#pragma unroll
            for (int n = 0; n < 32; ++n)
                acc[n] = fmaf(av[u], wc[u*32+n], acc[n]);
    }
    if (ok) {
        float4* op = (float4*)(out + (size_t)j*32);
#pragma unroll
        for (int q = 0; q < 8; ++q)
            op[q] = make_float4(acc[4*q], acc[4*q+1], acc[4*q+2], acc[4*q+3]);
    }
}

// ---------------- 2-voxel tap core, NCO-wide co tile ----------------
template<int CI, int CO, int NCO>
__device__ __forceinline__ void tap_fma(const float* __restrict__ in, const float* __restrict__ wtap,
                                        int s0, int s1, float (&acc)[2][NCO])
{
    for (int c0 = 0; c0 < CI; c0 += 16) {
        const float4* r0 = (const float4*)(in + (size_t)(s0 < 0 ? 0 : s0)*CI + c0);
        const float4* r1 = (const float4*)(in + (size_t)(s1 < 0 ? 0 : s1)*CI + c0);
        float4 a0[4], a1[4];
#pragma unroll
        for (int q = 0; q < 4; ++q) {
            a0[q] = (s0 >= 0) ? r0[q] : make_float4(0.f,0.f,0.f,0.f);
            a1[q] = (s1 >= 0) ? r1[q] : make_float4(0.f,0.f,0.f,0.f);
        }
        const float* wc = wtap + c0*CO;
#pragma unroll
        for (int u = 0; u < 16; ++u) {
            float x0 = ((const float*)a0)[u];
            float x1 = ((const float*)a1)[u];
            const float* wr = wc + u*CO;   // wave-uniform -> s_load
#pragma unroll
            for (int n = 0; n < NCO; ++n) {
                float wv = wr[n];
                acc[0][n] = fmaf(x0, wv, acc[0][n]);
                acc[1][n] = fmaf(x1, wv, acc[1][n]);
            }
        }
    }
}

template<int CO, int NCO>
__device__ __forceinline__ void store2(float* __restrict__ out, int co0, int j0, int j1,
                                       bool ok0, bool ok1, float (&acc)[2][NCO])
{
    if (ok0) {
        float4* op = (float4*)(out + (size_t)j0*CO + co0);
#pragma unroll
        for (int q = 0; q < NCO/4; ++q)
            op[q] = make_float4(acc[0][4*q], acc[0][4*q+1], acc[0][4*q+2], acc[0][4*q+3]);
    }
    if (ok1) {
        float4* op = (float4*)(out + (size_t)j1*CO + co0);
#pragma unroll
        for (int q = 0; q < NCO/4; ++q)
            op[q] = make_float4(acc[1][4*q], acc[1][4*q+1], acc[1][4*q+2], acc[1][4*q+3]);
    }
}

// ---------------- conv2: 2 vox/thread, co-tile 16 (round-8 proven) ----------------
template<int CI, int CO>
__global__ __launch_bounds__(256, 4)
void subm2v_k(const float* __restrict__ in, const int* __restrict__ grid2,
              const int* __restrict__ cellOf, const float* __restrict__ w,
              float* __restrict__ out, int nsites)
{
    const int tid = threadIdx.x;
    const int sbx = xcd_swizzle(blockIdx.x, gridDim.x);
    const int j0 = sbx*512 + tid, j1 = j0 + 256;
    const int co0 = blockIdx.y*16;
    const bool ok0 = j0 < nsites, ok1 = j1 < nsites;
    int cA = ok0 ? cellOf[j0] : 0;
    int cB = ok1 ? cellOf[j1] : 0;
    int z0 = cA >> 12, y0 = (cA >> 5) & 127, x0 = cA & 31;
    int z1 = cB >> 12, y1 = (cB >> 5) & 127, x1 = cB & 31;
    float acc[2][16];
#pragma unroll
    for (int v = 0; v < 2; ++v)
#pragma unroll
        for (int n = 0; n < 16; ++n) acc[v][n] = 0.f;

#pragma unroll 1
    for (int t = 0; t < 27; ++t) {
        int dz = t/9 - 1, dy = (t/3)%3 - 1, dx = t%3 - 1;
        int nz0 = z0+dz, ny0 = y0+dy, nx0 = x0+dx;
        int nz1 = z1+dz, ny1 = y1+dy, nx1 = x1+dx;
        int s0 = -1, s1 = -1;
        if (ok0 && nz0>=0 && nz0<AD && ny0>=0 && ny0<AH && nx0>=0 && nx0<AW)
            s0 = grid2[(nz0<<12)|(ny0<<5)|nx0];
        if (ok1 && nz1>=0 && nz1<AD && ny1>=0 && ny1<AH && nx1>=0 && nx1<AW)
            s1 = grid2[(nz1<<12)|(ny1<<5)|nx1];
        tap_fma<CI,CO,16>(in, w + (size_t)t*CI*CO + co0, s0, s1, acc);
    }
    store2<CO,16>(out, co0, j0, j1, ok0, ok1, acc);
}

// ---------------- chunk loader: 16 channels into a float4[4] register buffer ----------------
template<int CI>
__device__ __forceinline__ void loadc(float4 (&b)[4], const float* __restrict__ in, int s, int c0) {
    const float4* rp = (const float4*)(in + (size_t)(s < 0 ? 0 : s)*CI + c0);
#pragma unroll
    for (int q = 0; q < 4; ++q)
        b[q] = (s >= 0) ? rp[q] : make_float4(0.f,0.f,0.f,0.f);
}

// ---------------- conv3/conv4: 1 vox/thread, co-16, software-pipelined gathers ----------------
// Double register buffer: while chunk c's 256 FMAs run, the next chunk's gather
// (and at c==0, the next tap's grid2 index) are in flight -> gather latency hidden.
template<int CI, int CO>
__global__ __launch_bounds__(256, 4)
void subm_pipe_k(const float* __restrict__ in, const int* __restrict__ grid2,
                 const int* __restrict__ cellOf, const float* __restrict__ w,
                 float* __restrict__ out, int nsites)
{
    constexpr int NC = CI/16;
    const int tid = threadIdx.x;
    const int sbx = xcd_swizzle(blockIdx.x, gridDim.x);
    const int j = sbx*256 + tid;
    const int co0 = blockIdx.y*16;
    const bool ok = j < nsites;
    int cell = ok ? cellOf[j] : 0;
    const int z = cell >> 12, y = (cell >> 5) & 127, x = cell & 31;
    float acc[16];
#pragma unroll
    for (int n = 0; n < 16; ++n) acc[n] = 0.f;

    float4 buf[2][4];
    int sc = -1, sn = -1;
    {   // tap 0 index (exposed once)
        int nz = z-1, ny = y-1, nx = x-1;
        if (ok && nz>=0 && nz<AD && ny>=0 && ny<AH && nx>=0 && nx<AW)
            sc = grid2[(nz<<12)|(ny<<5)|nx];
    }
    loadc<CI>(buf[0], in, sc, 0);

#pragma unroll 1
    for (int t = 0; t < 27; ++t) {
#pragma unroll
        for (int c = 0; c < NC; ++c) {
            if (c == 0) {
                sn = -1;
                if (t < 26) {
                    int tt = t + 1;
                    int nz = z + tt/9 - 1, ny = y + (tt/3)%3 - 1, nx = x + tt%3 - 1;
                    if (ok && nz>=0 && nz<AD && ny>=0 && ny<AH && nx>=0 && nx<AW)
                        sn = grid2[(nz<<12)|(ny<<5)|nx];
                }
            }
            const int cur = c & 1;
            if (c + 1 < NC) loadc<CI>(buf[cur^1], in, sc, (c+1)*16);
            else            loadc<CI>(buf[cur^1], in, sn, 0);
            const float* wc = w + ((size_t)t*CI + c*16)*CO + co0;  // wave-uniform -> s_load
#pragma unroll
            for (int u = 0; u < 16; ++u) {
                float xv = ((const float*)buf[cur])[u];
                const float* wr = wc + u*CO;
#pragma unroll
                for (int n = 0; n < 16; ++n)
                    acc[n] = fmaf(xv, wr[n], acc[n]);
            }
        }
        sc = sn;
    }
    if (ok) {
        float4* op = (float4*)(out + (size_t)j*CO + co0);
#pragma unroll
        for (int q = 0; q < 4; ++q)
            op[q] = make_float4(acc[4*q], acc[4*q+1], acc[4*q+2], acc[4*q+3]);
    }
}

// ---------------- conv5: k3 s2 p1 sparse-in dense-out, tap-split, XCD-swizzled ----------------
template<int CI, int CO>
__global__ __launch_bounds__(256, 3)
void conv5s_k(const float* __restrict__ in, const int* __restrict__ grid2,
              const float* __restrict__ w, float* __restrict__ part, int tg)
{
    const int tid = threadIdx.x;
    const int sbx = xcd_swizzle(blockIdx.x, gridDim.x);
    const int o0 = sbx*512 + tid, o1 = o0 + 256;
    const int co0 = blockIdx.y*32;
    const int g = blockIdx.z;
    const int t0 = g*tg, t1 = (t0 + tg < 27) ? (t0 + tg) : 27;
    int oz0 = o0 >> 10, oy0 = (o0 >> 4) & 63, ox0 = o0 & 15;
    int oz1 = o1 >> 10, oy1 = (o1 >> 4) & 63, ox1 = o1 & 15;
    float acc[2][32];
#pragma unroll
    for (int v = 0; v < 2; ++v)
#pragma unroll
        for (int n = 0; n < 32; ++n) acc[v][n] = 0.f;

#pragma unroll 1
    for (int t = t0; t < t1; ++t) {
        int dz = t/9 - 1, dy = (t/3)%3 - 1, dx = t%3 - 1;
        int iz0 = 2*oz0+dz, iy0 = 2*oy0+dy, ix0 = 2*ox0+dx;
        int iz1 = 2*oz1+dz, iy1 = 2*oy1+dy, ix1 = 2*ox1+dx;
        int s0 = -1, s1 = -1;
        if (iz0>=0 && iz0<AD && iy0>=0 && iy0<AH && ix0>=0 && ix0<AW)
            s0 = grid2[(iz0<<12)|(iy0<<5)|ix0];
        if (iz1>=0 && iz1<AD && iy1>=0 && iy1<AH && ix1>=0 && ix1<AW)
            s1 = grid2[(iz1<<12)|(iy1<<5)|ix1];
        tap_fma<CI,CO,32>(in, w + (size_t)t*CI*CO + co0, s0, s1, acc);
    }
    store2<CO,32>(part + (size_t)g*65536*CO, co0, o0, o1, true, true, acc);
}

// ---------------- LDS-tiled dense conv k3 s1 p1 for stage B (64,64,16) ----------------
template<int CI, int CO>
__global__ __launch_bounds__(256, 3)
void convB_tile_k(const float* __restrict__ in, const float* __restrict__ w,
                  const float* __restrict__ mask, float* __restrict__ out)
{
    constexpr int HY = 10, HX = 10;
    constexpr int NH = 600;          // 6*10*10
    constexpr int STR = 20;          // 16 ch + 4 pad floats
    __shared__ float sf[NH*STR];     // 48 KB

    const int tid = threadIdx.x;
    const int bx = blockIdx.x;                 // 0..255
    const int tx_ = bx & 1, ty_ = (bx >> 1) & 7, tz_ = bx >> 4;
    const int z0 = tz_*4, y0 = ty_*8, x0 = tx_*8;
    const int lz = tid >> 6, ly = (tid >> 3) & 7, lx = tid & 7;
    const int co0 = blockIdx.y*32;
    const int o = ((z0+lz)*64 + (y0+ly))*16 + (x0+lx);

    float acc[32];
#pragma unroll
    for (int n = 0; n < 32; ++n) acc[n] = 0.f;

    for (int c0 = 0; c0 < CI; c0 += 16) {
        __syncthreads();
        for (int i = tid; i < NH*4; i += 256) {
            int cell = i >> 2, q = i & 3;
            int hz = cell / 100; int rr = cell - hz*100; int hy = rr / 10; int hx = rr - hy*10;
            int gz = z0 + hz - 1, gy = y0 + hy - 1, gx = x0 + hx - 1;
            float4 v = make_float4(0.f,0.f,0.f,0.f);
            if (gz>=0 && gz<64 && gy>=0 && gy<64 && gx>=0 && gx<16)
                v = *(const float4*)(in + (size_t)((gz*64+gy)*16+gx)*CI + c0 + q*4);
            *(float4*)(&sf[cell*STR + q*4]) = v;
        }
        __syncthreads();
#pragma unroll 1
        for (int t = 0; t < 27; ++t) {
            int hz = lz + t/9, hy = ly + (t/3)%3, hx = lx + t%3;
            const float4* fp = (const float4*)(&sf[((hz*HY + hy)*HX + hx)*STR]);
            float4 f0 = fp[0], f1 = fp[1], f2 = fp[2], f3 = fp[3];
            float xv[16] = {f0.x,f0.y,f0.z,f0.w, f1.x,f1.y,f1.z,f1.w,
                            f2.x,f2.y,f2.z,f2.w, f3.x,f3.y,f3.z,f3.w};
            const float* wt = w + ((size_t)t*CI + c0)*CO + co0;  // wave-uniform -> s_load
#pragma unroll
            for (int u = 0; u < 16; ++u) {
                const float* wr = wt + u*CO;
#pragma unroll
                for (int n = 0; n < 32; ++n)
                    acc[n] = fmaf(xv[u], wr[n], acc[n]);
            }
        }
    }
    float mv = mask[o];
    float4* op = (float4*)(out + (size_t)o*CO + co0);
#pragma unroll
    for (int q = 0; q < 8; ++q)
        op[q] = make_float4(acc[4*q]*mv, acc[4*q+1]*mv, acc[4*q+2]*mv, acc[4*q+3]*mv);
}

// ---------------- dense conv, tap-split: 2 voxels/thread (conv8, stages C, D) ----------------
template<int CI, int CO, int K, int S, int PAD, int ID, int IH, int IW, int OD, int OH, int OW>
__global__ __launch_bounds__(256, 3)
void dense2v_k(const float* __restrict__ in, const float* __restrict__ w,
               float* __restrict__ part, int tg)
{
    constexpr int NT = K*K*K;
    constexpr int NV = OD*OH*OW;
    const int tid = threadIdx.x;
    const int o0 = blockIdx.x*512 + tid, o1 = o0 + 256;
    const int co0 = blockIdx.y*32;
    const int g = blockIdx.z;
    const int t0 = g*tg, t1 = (t0 + tg < NT) ? (t0 + tg) : NT;
    int oz0 = o0/(OH*OW), r0v = o0 - oz0*(OH*OW), oy0 = r0v/OW, ox0 = r0v - oy0*OW;
    int oz1 = o1/(OH*OW), r1v = o1 - oz1*(OH*OW), oy1 = r1v/OW, ox1 = r1v - oy1*OW;
    float acc[2][32];
#pragma unroll
    for (int v = 0; v < 2; ++v)
#pragma unroll
        for (int n = 0; n < 32; ++n) acc[v][n] = 0.f;

#pragma unroll 1
    for (int t = t0; t < t1; ++t) {
        int kz = t/(K*K), rr = t - kz*(K*K), ky = rr/K, kx = rr - ky*K;
        int iz0 = oz0*S + kz - PAD, iy0 = oy0*S + ky - PAD, ix0 = ox0*S + kx - PAD;
        int iz1 = oz1*S + kz - PAD, iy1 = oy1*S + ky - PAD, ix1 = ox1*S + kx - PAD;
        int s0 = -1, s1 = -1;
        if (iz0>=0 && iz0<ID && iy0>=0 && iy0<IH && ix0>=0 && ix0<IW)
            s0 = (iz0*IH + iy0)*IW + ix0;
        if (iz1>=0 && iz1<ID && iy1>=0 && iy1<IH && ix1>=0 && ix1<IW)
            s1 = (iz1*IH + iy1)*IW + ix1;
        tap_fma<CI,CO,32>(in, w + (size_t)t*CI*CO + co0, s0, s1, acc);
    }
    store2<CO,32>(part + (size_t)g*NV*CO, co0, o0, o1, true, true, acc);
}

// ---------------- reduce partials (+ optional mask) ----------------
__global__ __launch_bounds__(256)
void reduce_k(const float* __restrict__ part, float* __restrict__ out,
              const float* __restrict__ mask, int NV, int CO, int G)
{
    int e = blockIdx.x*256 + threadIdx.x;
    if (e >= NV*CO) return;
    float s = 0.f;
    for (int g = 0; g < G; ++g) s += part[(size_t)g*NV*CO + e];
    if (mask) s *= mask[e / CO];
    out[e] = s;
}

// ---------------- tiny-stage subm conv: thread = (voxel, tap, co), partial out ----------------
template<int CI, int CO, int D_, int H_, int W_>
__global__ __launch_bounds__(256)
void conv_ks_k(const float* __restrict__ in, const float* __restrict__ w,
               float* __restrict__ part)
{
    constexpr int NV = D_*H_*W_;
    int idx = blockIdx.x*256 + threadIdx.x;
    if (idx >= NV*27*CO) return;
    int co = idx % CO;
    int rest = idx / CO;
    int t = rest % 27;
    int vox = rest / 27;
    int z = vox/(H_*W_), rv = vox - z*(H_*W_), y = rv/W_, x = rv - y*W_;
    int iz = z + t/9 - 1, iy = y + (t/3)%3 - 1, ix = x + t%3 - 1;
    float a = 0.f;
    if (iz>=0 && iz<D_ && iy>=0 && iy<H_ && ix>=0 && ix<W_) {
        const float4* xp = (const float4*)(in + (size_t)((iz*H_+iy)*W_+ix)*CI);
        const float* wp = w + (size_t)t*CI*CO + co;
#pragma unroll 4
        for (int c4 = 0; c4 < CI/4; ++c4) {
            float4 xv = xp[c4];
            a = fmaf(xv.x, wp[(size_t)(4*c4+0)*CO], a);
            a = fmaf(xv.y, wp[(size_t)(4*c4+1)*CO], a);
            a = fmaf(xv.z, wp[(size_t)(4*c4+2)*CO], a);
            a = fmaf(xv.w, wp[(size_t)(4*c4+3)*CO], a);
        }
    }
    part[((size_t)t*NV + vox)*CO + co] = a;
}

// ---------------- masks / pools / deconv ----------------
__global__ void mask_from_gridA_k(const int* __restrict__ grid, float* __restrict__ m1) {
    int o = blockIdx.x*256 + threadIdx.x;
    if (o >= 64*64*16) return;
    int oz = o >> 10, r = o & 1023, oy = r >> 4, ox = r & 15;
    int any = 0;
    for (int kz=0;kz<3;++kz) for(int ky=0;ky<3;++ky) for(int kx=0;kx<3;++kx){
        int iz=2*oz+kz-1, iy=2*oy+ky-1, ix=2*ox+kx-1;
        if (iz>=0&&iz<AD&&iy>=0&&iy<AH&&ix>=0&&ix<AW)
            any |= (grid[(iz*AH+iy)*AW+ix] >= 0) ? 1 : 0;
    }
    m1[o] = any ? 1.f : 0.f;
}

__global__ void mask_pool2_k(const float* __restrict__ mi, float* __restrict__ mo,
                             int OD,int OH,int OW) {
    int o = blockIdx.x*256 + threadIdx.x;
    if (o >= OD*OH*OW) return;
    int oz = o/(OH*OW); int r = o - oz*(OH*OW); int oy = r/OW, ox = r - oy*OW;
    int IH = OH*2, IW = OW*2;
    int any = 0;
    for (int dz=0;dz<2;++dz)for(int dy=0;dy<2;++dy)for(int dx=0;dx<2;++dx){
        int ii = ((2*oz+dz)*IH + (2*oy+dy))*IW + (2*ox+dx);
        any |= (mi[ii] > 0.f) ? 1 : 0;
    }
    mo[o] = any ? 1.f : 0.f;
}

template<int C>
__global__ void maxpool2_k(const float* __restrict__ x, const float* __restrict__ m,
                           float* __restrict__ out, int OD,int OH,int OW) {
    int idx = blockIdx.x*256 + threadIdx.x;
    int total = OD*OH*OW*C;
    if (idx >= total) return;
    int o = idx / C, c = idx - o*C;
    int oz = o/(OH*OW); int r = o - oz*(OH*OW); int oy = r/OW, ox = r - oy*OW;
    int IH = OH*2, IW = OW*2;
    float best = -3.402823466e38f; int any = 0;
    for (int dz=0;dz<2;++dz)for(int dy=0;dy<2;++dy)for(int dx=0;dx<2;++dx){
        int ii = ((2*oz+dz)*IH + (2*oy+dy))*IW + (2*ox+dx);
        if (m[ii] > 0.f) { any = 1; best = fmaxf(best, x[(size_t)ii*C + c]); }
    }
    out[idx] = any ? best : 0.f;
}

// conv_transpose k=2 s=2 VALID, transpose_kernel=False: out[2i+d] = x[i] . w[1-d]
template<int CI, int CO>
__global__ void deconv2x_k(const float* __restrict__ x, const float* __restrict__ w,
                           const float* __restrict__ m, float* __restrict__ out,
                           int OD,int OH,int OW) {
    int idx = blockIdx.x*256 + threadIdx.x;
    int total = OD*OH*OW*CO;
    if (idx >= total) return;
    int o = idx / CO, co = idx - o*CO;
    if (!(m[o] > 0.f)) { out[idx] = 0.f; return; }
    int oz = o/(OH*OW); int r = o - oz*(OH*OW); int oy = r/OW, ox = r - oy*OW;
    int IH = OH>>1, IW = OW>>1;
    int iz=oz>>1, iy=oy>>1, ix=ox>>1;
    int wt = ((1-(oz&1))*2 + (1-(oy&1)))*2 + (1-(ox&1));
    const float* xp = x + (size_t)((iz*IH+iy)*IW+ix)*CI;
    const float* wp = w + (size_t)wt*CI*CO + co;
    float acc = 0.f;
#pragma unroll 4
    for (int ci=0;ci<CI;++ci) acc = fmaf(xp[ci], wp[(size_t)ci*CO], acc);
    out[idx] = acc;
}

// ---------------- launch ----------------
extern "C" void kernel_launch(void* const* d_in, const int* in_sizes, int n_in,
                              void* d_out, int out_size, void* d_ws, size_t ws_size,
                              hipStream_t stream)
{
    const float* features = (const float*)d_in[0];
    const int*   coors    = (const int*)d_in[1];
    const int N = in_sizes[0] / 3;
    const float* w1  = (const float*)d_in[3];
    const float* w2  = (const float*)d_in[4];
    const float* w3  = (const float*)d_in[5];
    const float* w4  = (const float*)d_in[6];
    const float* w5  = (const float*)d_in[7];
    const float* w6  = (const float*)d_in[8];
    const float* w7  = (const float*)d_in[9];
    const float* w8  = (const float*)d_in[10];
    const float* w9  = (const float*)d_in[11];
    const float* w10 = (const float*)d_in[12];
    const float* w11 = (const float*)d_in[13];
    const float* w12 = (const float*)d_in[14];
    const float* w13 = (const float*)d_in[15];
    const float* w14 = (const float*)d_in[16];
    const float* w15 = (const float*)d_in[17];
    const float* w16 = (const float*)d_in[18];
    const float* w17 = (const float*)d_in[19];
    const float* w18 = (const float*)d_in[20];

    char* p = (char*)d_ws;
    auto alloc = [&](size_t bytes)->void* {
        void* r = (void*)p; p += (bytes + 255) & ~(size_t)255; return r;
    };
    int*   gridA = (int*)  alloc((size_t)NCELL*4);
    int*   grid2 = (int*)  alloc((size_t)NCELL*4);
    int*   partS = (int*)  alloc((size_t)512*4);
    int*   cellOf= (int*)  alloc((size_t)N*4);
    float* featS = (float*)alloc((size_t)N*4*4);
    float* sA0   = (float*)alloc((size_t)N*64*4);   // also conv5 partial region
    float* sA1   = (float*)alloc((size_t)N*64*4);
    float* xB0   = (float*)alloc((size_t)65536*96*4);
    float* xB1   = (float*)alloc((size_t)65536*96*4);
    float* m1    = (float*)alloc((size_t)65536*4);
    float* xC0   = (float*)alloc((size_t)8192*128*4);
    float* xC1   = (float*)alloc((size_t)8192*128*4);
    float* m2    = (float*)alloc((size_t)8192*4);
    float* xD0   = (float*)alloc((size_t)1024*160*4);
    float* xD1   = (float*)alloc((size_t)1024*160*4);
    float* m3    = (float*)alloc((size_t)1024*4);
    float* xE0   = (float*)alloc((size_t)128*192*4);
    float* xE1   = (float*)alloc((size_t)128*192*4);
    float* m4    = (float*)alloc((size_t)128*4);
    float* xF0   = (float*)alloc((size_t)16*224*4);
    float* xF1   = (float*)alloc((size_t)16*224*4);
    float* m5    = (float*)alloc((size_t)16*4);
    float* dT1   = (float*)alloc((size_t)128*128*4);
    if ((size_t)(p - (char*)d_ws) > ws_size) return;
    float* part  = sA0;   // conv5/dense partial scratch (after stage A consumed)

    // ---- grid + spatial sort
    hipMemsetAsync(gridA, 0xFF, (size_t)NCELL*4, stream);
    build_grid_k<<<(N+255)/256,256,0,stream>>>(coors, gridA, N);
    scan1_k<<<512,256,0,stream>>>(gridA, partS);
    scan2_k<<<1,512,0,stream>>>(partS);
    scan3_k<<<512,256,0,stream>>>(gridA, partS, features, grid2, cellOf, featS);

    // ---- stage A (sorted, XCD-swizzled): conv2 co-16 2vox; conv3/4 pipelined 1vox co-16
    int gx2 = (N + 511) / 512;   // 2-vox site-blocks
    int gx1 = (N + 255) / 256;   // 1-vox site-blocks
    subm_first_k<<<(N+255)/256,256,0,stream>>>(featS, grid2, cellOf, w1, sA0, N);
    subm2v_k<32,32><<<dim3(gx2,2),256,0,stream>>>(sA0, grid2, cellOf, w2, sA1, N);
    subm_pipe_k<32,64><<<dim3(gx1,4),256,0,stream>>>(sA1, grid2, cellOf, w3, sA0, N);
    subm_pipe_k<64,64><<<dim3(gx1,4),256,0,stream>>>(sA0, grid2, cellOf, w4, sA1, N);

    // ---- conv5 (reads sA1; partials in sA0: 2*16.8MB <= 38.4MB) -> xB0
    conv5s_k<64,64><<<dim3(128,2,2),256,0,stream>>>(sA1, grid2, w5, sA0, 14);
    reduce_k<<<(65536*64+255)/256,256,0,stream>>>(sA0, xB0, nullptr, 65536, 64, 2);
    mask_from_gridA_k<<<256,256,0,stream>>>(gridA, m1);

    // ---- stage B (64,64,16): LDS-tiled, all 27 taps in one pass, mask fused
    convB_tile_k<64,96><<<dim3(256,3),256,0,stream>>>(xB0, w6, m1, xB1);
    convB_tile_k<96,96><<<dim3(256,3),256,0,stream>>>(xB1, w7, m1, xB0);

    // ---- conv8: k2 s2 VALID (naturally masked), 2-vox G=8
    dense2v_k<96,96,2,2,0, 64,64,16, 32,32,8><<<dim3(16,3,8),256,0,stream>>>(xB0, w8, part, 1);
    reduce_k<<<(8192*96+255)/256,256,0,stream>>>(part, xC0, nullptr, 8192, 96, 8);
    mask_pool2_k<<<(8192+255)/256,256,0,stream>>>(m1, m2, 32,32,8);

    // ---- stage C (32,32,8), 2-vox G=9 (partials 9*4.2MB = 37.7MB <= 38.4)
    dense2v_k<96,128,3,1,1, 32,32,8, 32,32,8><<<dim3(16,4,9),256,0,stream>>>(xC0, w9, part, 3);
    reduce_k<<<(8192*128+255)/256,256,0,stream>>>(part, xC1, m2, 8192, 128, 9);
    dense2v_k<128,128,3,1,1, 32,32,8, 32,32,8><<<dim3(16,4,9),256,0,stream>>>(xC1, w10, part, 3);
    reduce_k<<<(8192*128+255)/256,256,0,stream>>>(part, xC0, m2, 8192, 128, 9);

    // ---- C -> D maxpool + m3
    mask_pool2_k<<<(1024+255)/256,256,0,stream>>>(m2, m3, 16,16,4);
    maxpool2_k<128><<<(1024*128+255)/256,256,0,stream>>>(xC0, m2, xD0, 16,16,4);

    // ---- stage D (16,16,4), 2-vox G=27
    dense2v_k<128,160,3,1,1, 16,16,4, 16,16,4><<<dim3(2,5,27),256,0,stream>>>(xD0, w11, part, 1);
    reduce_k<<<(1024*160+255)/256,256,0,stream>>>(part, xD1, m3, 1024, 160, 27);
    dense2v_k<160,160,3,1,1, 16,16,4, 16,16,4><<<dim3(2,5,27),256,0,stream>>>(xD1, w12, part, 1);
    reduce_k<<<(1024*160+255)/256,256,0,stream>>>(part, xD0, m3, 1024, 160, 27);

    // ---- D -> E maxpool + m4
    mask_pool2_k<<<1,256,0,stream>>>(m3, m4, 8,8,2);
    maxpool2_k<160><<<(128*160+255)/256,256,0,stream>>>(xD0, m3, xE0, 8,8,2);

    // ---- stage E (8,8,2): thread-per-(vox,tap,co) split
    conv_ks_k<160,192, 8,8,2><<<(128*27*192+255)/256,256,0,stream>>>(xE0, w13, part);
    reduce_k<<<(128*192+255)/256,256,0,stream>>>(part, xE1, m4, 128, 192, 27);
    conv_ks_k<192,192, 8,8,2><<<(128*27*192+255)/256,256,0,stream>>>(xE1, w14, part);
    reduce_k<<<(128*192+255)/256,256,0,stream>>>(part, xE0, m4, 128, 192, 27);

    // ---- E -> F maxpool + m5
    mask_pool2_k<<<1,256,0,stream>>>(m4, m5, 4,4,1);
    maxpool2_k<192><<<(16*192+255)/256,256,0,stream>>>(xE0, m4, xF0, 4,4,1);

    // ---- stage F (4,4,1)
    conv_ks_k<192,224, 4,4,1><<<(16*27*224+255)/256,256,0,stream>>>(xF0, w15, part);
    reduce_k<<<(16*224+255)/256,256,0,stream>>>(part, xF1, m5, 16, 224, 27);
    conv_ks_k<224,224, 4,4,1><<<(16*27*224+255)/256,256,0,stream>>>(xF1, w16, part);
    reduce_k<<<(16*224+255)/256,256,0,stream>>>(part, xF0, m5, 16, 224, 27);

    // ---- deconvs (taps flipped), masked by m4 then m3; final write = d_out
    deconv2x_k<224,128><<<(8*8*2*128+255)/256,256,0,stream>>>(xF0, w17, m4, dT1, 8,8,2);
    deconv2x_k<128,64><<<(16*16*4*64+255)/256,256,0,stream>>>(dT1, w18, m3, (float*)d_out, 16,16,4);
}

// Round 12
// 2833.141 us; speedup vs baseline: 1.7250x; 1.7250x over previous
//
#include <hip/hip_runtime.h>
#include <cstdint>
#include <cstddef>

// Stage-A dense grid dims: flat cell = (z<<12)|(y<<5)|x
#define AD 128
#define AH 128
#define AW 32
#define NCELL (AD*AH*AW)   // 524288

// XCD-contiguous block swizzle: blocks with equal (bid&7) — same XCD under
// round-robin dispatch — get CONTIGUOUS logical ranges. Perf-only remap.
__device__ __forceinline__ int xcd_swizzle(int bx, int nb) {
    int xcd = bx & 7, slot = bx >> 3;
    int base = nb >> 3, rem = nb & 7;
    return (xcd < rem) ? (xcd*(base+1) + slot) : (rem + xcd*base + slot);
}

// ---------------- setup: grid + spatial sort (occupancy scan) ----------------
__global__ void build_grid_k(const int* __restrict__ coors, int* __restrict__ grid, int N) {
    int i = blockIdx.x * 256 + threadIdx.x;
    if (i >= N) return;
    int z = coors[i*4+1], y = coors[i*4+2], x = coors[i*4+3];
    grid[(z*AH + y)*AW + x] = i;
}

__global__ __launch_bounds__(256) void scan1_k(const int* __restrict__ grid, int* __restrict__ partial) {
    __shared__ int sm[256];
    int tid = threadIdx.x;
    int base = blockIdx.x*1024 + tid*4;
    int c = 0;
#pragma unroll
    for (int k = 0; k < 4; ++k) c += (grid[base+k] >= 0) ? 1 : 0;
    sm[tid] = c; __syncthreads();
    for (int off = 128; off; off >>= 1) {
        if (tid < off) sm[tid] += sm[tid+off];
        __syncthreads();
    }
    if (tid == 0) partial[blockIdx.x] = sm[0];
}

__global__ __launch_bounds__(512) void scan2_k(int* __restrict__ partial) {
    __shared__ int sm[512];
    int tid = threadIdx.x;
    int own = partial[tid];
    sm[tid] = own; __syncthreads();
    for (int off = 1; off < 512; off <<= 1) {
        int v = (tid >= off) ? sm[tid-off] : 0;
        __syncthreads();
        sm[tid] += v;
        __syncthreads();
    }
    partial[tid] = sm[tid] - own;   // exclusive
}

__global__ __launch_bounds__(256) void scan3_k(const int* __restrict__ grid, const int* __restrict__ partial,
                                               const float* __restrict__ features,
                                               int* __restrict__ grid2, int* __restrict__ cellOf,
                                               float* __restrict__ featS) {
    __shared__ int sm[256];
    int tid = threadIdx.x;
    int base = blockIdx.x*1024 + tid*4;
    int olds[4]; int c = 0;
#pragma unroll
    for (int k = 0; k < 4; ++k) { olds[k] = grid[base+k]; c += (olds[k] >= 0) ? 1 : 0; }
    int own = c;
    sm[tid] = c; __syncthreads();
    for (int off = 1; off < 256; off <<= 1) {
        int v = (tid >= off) ? sm[tid-off] : 0;
        __syncthreads();
        sm[tid] += v;
        __syncthreads();
    }
    int j = partial[blockIdx.x] + sm[tid] - own;
#pragma unroll
    for (int k = 0; k < 4; ++k) {
        int cell = base + k, old = olds[k];
        if (old >= 0) {
            grid2[cell] = j; cellOf[j] = cell;
            featS[j*4+0] = features[old*3+0];
            featS[j*4+1] = features[old*3+1];
            featS[j*4+2] = features[old*3+2];
            featS[j*4+3] = 0.f;
            ++j;
        } else grid2[cell] = -1;
    }
}

// ---------------- first layer: CI=3 (stride 4), co-16 split ----------------
__global__ __launch_bounds__(256, 6)
void subm_first_k(const float* __restrict__ featS, const int* __restrict__ grid2,
                  const int* __restrict__ cellOf, const float* __restrict__ w,
                  float* __restrict__ out, int nsites)
{
    int j = blockIdx.x*256 + threadIdx.x;
    const int co0 = blockIdx.y*16;
    bool ok = j < nsites;
    int cell = ok ? cellOf[j] : 0;
    int z = cell >> 12, y = (cell >> 5) & 127, x = cell & 31;
    float acc[16];
#pragma unroll
    for (int n = 0; n < 16; ++n) acc[n] = 0.f;
    for (int t = 0; t < 27; ++t) {
        int nz = z + t/9 - 1, ny = y + (t/3)%3 - 1, nx = x + t%3 - 1;
        int s = -1;
        if (ok && nz>=0 && nz<AD && ny>=0 && ny<AH && nx>=0 && nx<AW)
            s = grid2[(nz<<12)|(ny<<5)|nx];
        float4 v = make_float4(0.f,0.f,0.f,0.f);
        if (s >= 0) v = ((const float4*)featS)[s];
        const float* wc = w + t*3*32 + co0;
        float av[3] = {v.x, v.y, v.z};
#pragma unroll
        for (int u = 0; u < 3; ++u)
#pragma unroll
            for (int n = 0; n < 16; ++n)
                acc[n] = fmaf(av[u], wc[u*32+n], acc[n]);
    }
    if (ok) {
        float4* op = (float4*)(out + (size_t)j*32 + co0);
#pragma unroll
        for (int q = 0; q < 4; ++q)
            op[q] = make_float4(acc[4*q], acc[4*q+1], acc[4*q+2], acc[4*q+3]);
    }
}

// ---------------- stage-A submanifold conv: 1 vox/thread, co-tile 16, max TLP ----------------
// acc[16] ~ 48 VGPR natural pressure; (256,6) budget 85 -> no spill, 6 waves/SIMD
// possible. conv3/4: 2344 blocks (9.2/CU) -> latency hidden by wave count.
template<int CI, int CO>
__global__ __launch_bounds__(256, 6)
void subm1c_k(const float* __restrict__ in, const int* __restrict__ grid2,
              const int* __restrict__ cellOf, const float* __restrict__ w,
              float* __restrict__ out, int nsites)
{
    const int tid = threadIdx.x;
    const int sbx = xcd_swizzle(blockIdx.x, gridDim.x);
    const int j = sbx*256 + tid;
    const int co0 = blockIdx.y*16;
    const bool ok = j < nsites;
    int cell = ok ? cellOf[j] : 0;
    const int z = cell >> 12, y = (cell >> 5) & 127, x = cell & 31;
    float acc[16];
#pragma unroll
    for (int n = 0; n < 16; ++n) acc[n] = 0.f;

#pragma unroll 1
    for (int t = 0; t < 27; ++t) {
        int dz = t/9 - 1, dy = (t/3)%3 - 1, dx = t%3 - 1;
        int nz = z+dz, ny = y+dy, nx = x+dx;
        int s = -1;
        if (ok && nz>=0 && nz<AD && ny>=0 && ny<AH && nx>=0 && nx<AW)
            s = grid2[(nz<<12)|(ny<<5)|nx];
        for (int c0 = 0; c0 < CI; c0 += 16) {
            const float4* rp = (const float4*)(in + (size_t)(s < 0 ? 0 : s)*CI + c0);
            float4 a0 = make_float4(0.f,0.f,0.f,0.f), a1 = a0, a2 = a0, a3 = a0;
            if (s >= 0) { a0 = rp[0]; a1 = rp[1]; a2 = rp[2]; a3 = rp[3]; }
            float xv[16] = {a0.x,a0.y,a0.z,a0.w, a1.x,a1.y,a1.z,a1.w,
                            a2.x,a2.y,a2.z,a2.w, a3.x,a3.y,a3.z,a3.w};
            const float* wc = w + ((size_t)t*CI + c0)*CO + co0;   // wave-uniform -> s_load
#pragma unroll
            for (int u = 0; u < 16; ++u) {
                const float* wr = wc + u*CO;
#pragma unroll
                for (int n = 0; n < 16; ++n)
                    acc[n] = fmaf(xv[u], wr[n], acc[n]);
            }
        }
    }
    if (ok) {
        float4* op = (float4*)(out + (size_t)j*CO + co0);
#pragma unroll
        for (int q = 0; q < 4; ++q)
            op[q] = make_float4(acc[4*q], acc[4*q+1], acc[4*q+2], acc[4*q+3]);
    }
}

// ---------------- 2-voxel tap core, NCO-wide co tile (conv5 / dense stages) ----------------
template<int CI, int CO, int NCO>
__device__ __forceinline__ void tap_fma(const float* __restrict__ in, const float* __restrict__ wtap,
                                        int s0, int s1, float (&acc)[2][NCO])
{
    for (int c0 = 0; c0 < CI; c0 += 16) {
        const float4* r0 = (const float4*)(in + (size_t)(s0 < 0 ? 0 : s0)*CI + c0);
        const float4* r1 = (const float4*)(in + (size_t)(s1 < 0 ? 0 : s1)*CI + c0);
        float4 a0[4], a1[4];
#pragma unroll
        for (int q = 0; q < 4; ++q) {
            a0[q] = (s0 >= 0) ? r0[q] : make_float4(0.f,0.f,0.f,0.f);
            a1[q] = (s1 >= 0) ? r1[q] : make_float4(0.f,0.f,0.f,0.f);
        }
        const float* wc = wtap + c0*CO;
#pragma unroll
        for (int u = 0; u < 16; ++u) {
            float x0 = ((const float*)a0)[u];
            float x1 = ((const float*)a1)[u];
            const float* wr = wc + u*CO;   // wave-uniform -> s_load
#pragma unroll
            for (int n = 0; n < NCO; ++n) {
                float wv = wr[n];
                acc[0][n] = fmaf(x0, wv, acc[0][n]);
                acc[1][n] = fmaf(x1, wv, acc[1][n]);
            }
        }
    }
}

template<int CO, int NCO>
__device__ __forceinline__ void store2(float* __restrict__ out, int co0, int j0, int j1,
                                       bool ok0, bool ok1, float (&acc)[2][NCO])
{
    if (ok0) {
        float4* op = (float4*)(out + (size_t)j0*CO + co0);
#pragma unroll
        for (int q = 0; q < NCO/4; ++q)
            op[q] = make_float4(acc[0][4*q], acc[0][4*q+1], acc[0][4*q+2], acc[0][4*q+3]);
    }
    if (ok1) {
        float4* op = (float4*)(out + (size_t)j1*CO + co0);
#pragma unroll
        for (int q = 0; q < NCO/4; ++q)
            op[q] = make_float4(acc[1][4*q], acc[1][4*q+1], acc[1][4*q+2], acc[1][4*q+3]);
    }
}

// ---------------- conv5: k3 s2 p1 sparse-in dense-out, tap-split, XCD-swizzled ----------------
template<int CI, int CO>
__global__ __launch_bounds__(256, 3)
void conv5s_k(const float* __restrict__ in, const int* __restrict__ grid2,
              const float* __restrict__ w, float* __restrict__ part, int tg)
{
    const int tid = threadIdx.x;
    const int sbx = xcd_swizzle(blockIdx.x, gridDim.x);
    const int o0 = sbx*512 + tid, o1 = o0 + 256;
    const int co0 = blockIdx.y*32;
    const int g = blockIdx.z;
    const int t0 = g*tg, t1 = (t0 + tg < 27) ? (t0 + tg) : 27;
    int oz0 = o0 >> 10, oy0 = (o0 >> 4) & 63, ox0 = o0 & 15;
    int oz1 = o1 >> 10, oy1 = (o1 >> 4) & 63, ox1 = o1 & 15;
    float acc[2][32];
#pragma unroll
    for (int v = 0; v < 2; ++v)
#pragma unroll
        for (int n = 0; n < 32; ++n) acc[v][n] = 0.f;

#pragma unroll 1
    for (int t = t0; t < t1; ++t) {
        int dz = t/9 - 1, dy = (t/3)%3 - 1, dx = t%3 - 1;
        int iz0 = 2*oz0+dz, iy0 = 2*oy0+dy, ix0 = 2*ox0+dx;
        int iz1 = 2*oz1+dz, iy1 = 2*oy1+dy, ix1 = 2*ox1+dx;
        int s0 = -1, s1 = -1;
        if (iz0>=0 && iz0<AD && iy0>=0 && iy0<AH && ix0>=0 && ix0<AW)
            s0 = grid2[(iz0<<12)|(iy0<<5)|ix0];
        if (iz1>=0 && iz1<AD && iy1>=0 && iy1<AH && ix1>=0 && ix1<AW)
            s1 = grid2[(iz1<<12)|(iy1<<5)|ix1];
        tap_fma<CI,CO,32>(in, w + (size_t)t*CI*CO + co0, s0, s1, acc);
    }
    store2<CO,32>(part + (size_t)g*65536*CO, co0, o0, o1, true, true, acc);
}

// ---------------- LDS-tiled dense conv k3 s1 p1 for stage B (64,64,16) ----------------
template<int CI, int CO>
__global__ __launch_bounds__(256, 3)
void convB_tile_k(const float* __restrict__ in, const float* __restrict__ w,
                  const float* __restrict__ mask, float* __restrict__ out)
{
    constexpr int HY = 10, HX = 10;
    constexpr int NH = 600;          // 6*10*10
    constexpr int STR = 20;          // 16 ch + 4 pad floats
    __shared__ float sf[NH*STR];     // 48 KB

    const int tid = threadIdx.x;
    const int bx = blockIdx.x;                 // 0..255
    const int tx_ = bx & 1, ty_ = (bx >> 1) & 7, tz_ = bx >> 4;
    const int z0 = tz_*4, y0 = ty_*8, x0 = tx_*8;
    const int lz = tid >> 6, ly = (tid >> 3) & 7, lx = tid & 7;
    const int co0 = blockIdx.y*32;
    const int o = ((z0+lz)*64 + (y0+ly))*16 + (x0+lx);

    float acc[32];
#pragma unroll
    for (int n = 0; n < 32; ++n) acc[n] = 0.f;

    for (int c0 = 0; c0 < CI; c0 += 16) {
        __syncthreads();
        for (int i = tid; i < NH*4; i += 256) {
            int cell = i >> 2, q = i & 3;
            int hz = cell / 100; int rr = cell - hz*100; int hy = rr / 10; int hx = rr - hy*10;
            int gz = z0 + hz - 1, gy = y0 + hy - 1, gx = x0 + hx - 1;
            float4 v = make_float4(0.f,0.f,0.f,0.f);
            if (gz>=0 && gz<64 && gy>=0 && gy<64 && gx>=0 && gx<16)
                v = *(const float4*)(in + (size_t)((gz*64+gy)*16+gx)*CI + c0 + q*4);
            *(float4*)(&sf[cell*STR + q*4]) = v;
        }
        __syncthreads();
#pragma unroll 1
        for (int t = 0; t < 27; ++t) {
            int hz = lz + t/9, hy = ly + (t/3)%3, hx = lx + t%3;
            const float4* fp = (const float4*)(&sf[((hz*HY + hy)*HX + hx)*STR]);
            float4 f0 = fp[0], f1 = fp[1], f2 = fp[2], f3 = fp[3];
            float xv[16] = {f0.x,f0.y,f0.z,f0.w, f1.x,f1.y,f1.z,f1.w,
                            f2.x,f2.y,f2.z,f2.w, f3.x,f3.y,f3.z,f3.w};
            const float* wt = w + ((size_t)t*CI + c0)*CO + co0;  // wave-uniform -> s_load
#pragma unroll
            for (int u = 0; u < 16; ++u) {
                const float* wr = wt + u*CO;
#pragma unroll
                for (int n = 0; n < 32; ++n)
                    acc[n] = fmaf(xv[u], wr[n], acc[n]);
            }
        }
    }
    float mv = mask[o];
    float4* op = (float4*)(out + (size_t)o*CO + co0);
#pragma unroll
    for (int q = 0; q < 8; ++q)
        op[q] = make_float4(acc[4*q]*mv, acc[4*q+1]*mv, acc[4*q+2]*mv, acc[4*q+3]*mv);
}

// ---------------- dense conv, tap-split: 2 voxels/thread (conv8, stages C, D) ----------------
template<int CI, int CO, int K, int S, int PAD, int ID, int IH, int IW, int OD, int OH, int OW>
__global__ __launch_bounds__(256, 3)
void dense2v_k(const float* __restrict__ in, const float* __restrict__ w,
               float* __restrict__ part, int tg)
{
    constexpr int NT = K*K*K;
    constexpr int NV = OD*OH*OW;
    const int tid = threadIdx.x;
    const int o0 = blockIdx.x*512 + tid, o1 = o0 + 256;
    const int co0 = blockIdx.y*32;
    const int g = blockIdx.z;
    const int t0 = g*tg, t1 = (t0 + tg < NT) ? (t0 + tg) : NT;
    int oz0 = o0/(OH*OW), r0v = o0 - oz0*(OH*OW), oy0 = r0v/OW, ox0 = r0v - oy0*OW;
    int oz1 = o1/(OH*OW), r1v = o1 - oz1*(OH*OW), oy1 = r1v/OW, ox1 = r1v - oy1*OW;
    float acc[2][32];
#pragma unroll
    for (int v = 0; v < 2; ++v)
#pragma unroll
        for (int n = 0; n < 32; ++n) acc[v][n] = 0.f;

#pragma unroll 1
    for (int t = t0; t < t1; ++t) {
        int kz = t/(K*K), rr = t - kz*(K*K), ky = rr/K, kx = rr - ky*K;
        int iz0 = oz0*S + kz - PAD, iy0 = oy0*S + ky - PAD, ix0 = ox0*S + kx - PAD;
        int iz1 = oz1*S + kz - PAD, iy1 = oy1*S + ky - PAD, ix1 = ox1*S + kx - PAD;
        int s0 = -1, s1 = -1;
        if (iz0>=0 && iz0<ID && iy0>=0 && iy0<IH && ix0>=0 && ix0<IW)
            s0 = (iz0*IH + iy0)*IW + ix0;
        if (iz1>=0 && iz1<ID && iy1>=0 && iy1<IH && ix1>=0 && ix1<IW)
            s1 = (iz1*IH + iy1)*IW + ix1;
        tap_fma<CI,CO,32>(in, w + (size_t)t*CI*CO + co0, s0, s1, acc);
    }
    store2<CO,32>(part + (size_t)g*NV*CO, co0, o0, o1, true, true, acc);
}

// ---------------- reduce partials (+ optional mask) ----------------
__global__ __launch_bounds__(256)
void reduce_k(const float* __restrict__ part, float* __restrict__ out,
              const float* __restrict__ mask, int NV, int CO, int G)
{
    int e = blockIdx.x*256 + threadIdx.x;
    if (e >= NV*CO) return;
    float s = 0.f;
    for (int g = 0; g < G; ++g) s += part[(size_t)g*NV*CO + e];
    if (mask) s *= mask[e / CO];
    out[e] = s;
}

// ---------------- tiny-stage subm conv: thread = (voxel, tap, co), partial out ----------------
template<int CI, int CO, int D_, int H_, int W_>
__global__ __launch_bounds__(256)
void conv_ks_k(const float* __restrict__ in, const float* __restrict__ w,
               float* __restrict__ part)
{
    constexpr int NV = D_*H_*W_;
    int idx = blockIdx.x*256 + threadIdx.x;
    if (idx >= NV*27*CO) return;
    int co = idx % CO;
    int rest = idx / CO;
    int t = rest % 27;
    int vox = rest / 27;
    int z = vox/(H_*W_), rv = vox - z*(H_*W_), y = rv/W_, x = rv - y*W_;
    int iz = z + t/9 - 1, iy = y + (t/3)%3 - 1, ix = x + t%3 - 1;
    float a = 0.f;
    if (iz>=0 && iz<D_ && iy>=0 && iy<H_ && ix>=0 && ix<W_) {
        const float4* xp = (const float4*)(in + (size_t)((iz*H_+iy)*W_+ix)*CI);
        const float* wp = w + (size_t)t*CI*CO + co;
#pragma unroll 4
        for (int c4 = 0; c4 < CI/4; ++c4) {
            float4 xv = xp[c4];
            a = fmaf(xv.x, wp[(size_t)(4*c4+0)*CO], a);
            a = fmaf(xv.y, wp[(size_t)(4*c4+1)*CO], a);
            a = fmaf(xv.z, wp[(size_t)(4*c4+2)*CO], a);
            a = fmaf(xv.w, wp[(size_t)(4*c4+3)*CO], a);
        }
    }
    part[((size_t)t*NV + vox)*CO + co] = a;
}

// ---------------- masks / pools / deconv ----------------
__global__ void mask_from_gridA_k(const int* __restrict__ grid, float* __restrict__ m1) {
    int o = blockIdx.x*256 + threadIdx.x;
    if (o >= 64*64*16) return;
    int oz = o >> 10, r = o & 1023, oy = r >> 4, ox = r & 15;
    int any = 0;
    for (int kz=0;kz<3;++kz) for(int ky=0;ky<3;++ky) for(int kx=0;kx<3;++kx){
        int iz=2*oz+kz-1, iy=2*oy+ky-1, ix=2*ox+kx-1;
        if (iz>=0&&iz<AD&&iy>=0&&iy<AH&&ix>=0&&ix<AW)
            any |= (grid[(iz*AH+iy)*AW+ix] >= 0) ? 1 : 0;
    }
    m1[o] = any ? 1.f : 0.f;
}

__global__ void mask_pool2_k(const float* __restrict__ mi, float* __restrict__ mo,
                             int OD,int OH,int OW) {
    int o = blockIdx.x*256 + threadIdx.x;
    if (o >= OD*OH*OW) return;
    int oz = o/(OH*OW); int r = o - oz*(OH*OW); int oy = r/OW, ox = r - oy*OW;
    int IH = OH*2, IW = OW*2;
    int any = 0;
    for (int dz=0;dz<2;++dz)for(int dy=0;dy<2;++dy)for(int dx=0;dx<2;++dx){
        int ii = ((2*oz+dz)*IH + (2*oy+dy))*IW + (2*ox+dx);
        any |= (mi[ii] > 0.f) ? 1 : 0;
    }
    mo[o] = any ? 1.f : 0.f;
}

template<int C>
__global__ void maxpool2_k(const float* __restrict__ x, const float* __restrict__ m,
                           float* __restrict__ out, int OD,int OH,int OW) {
    int idx = blockIdx.x*256 + threadIdx.x;
    int total = OD*OH*OW*C;
    if (idx >= total) return;
    int o = idx / C, c = idx - o*C;
    int oz = o/(OH*OW); int r = o - oz*(OH*OW); int oy = r/OW, ox = r - oy*OW;
    int IH = OH*2, IW = OW*2;
    float best = -3.402823466e38f; int any = 0;
    for (int dz=0;dz<2;++dz)for(int dy=0;dy<2;++dy)for(int dx=0;dx<2;++dx){
        int ii = ((2*oz+dz)*IH + (2*oy+dy))*IW + (2*ox+dx);
        if (m[ii] > 0.f) { any = 1; best = fmaxf(best, x[(size_t)ii*C + c]); }
    }
    out[idx] = any ? best : 0.f;
}

// conv_transpose k=2 s=2 VALID, transpose_kernel=False: out[2i+d] = x[i] . w[1-d]
template<int CI, int CO>
__global__ void deconv2x_k(const float* __restrict__ x, const float* __restrict__ w,
                           const float* __restrict__ m, float* __restrict__ out,
                           int OD,int OH,int OW) {
    int idx = blockIdx.x*256 + threadIdx.x;
    int total = OD*OH*OW*CO;
    if (idx >= total) return;
    int o = idx / CO, co = idx - o*CO;
    if (!(m[o] > 0.f)) { out[idx] = 0.f; return; }
    int oz = o/(OH*OW); int r = o - oz*(OH*OW); int oy = r/OW, ox = r - oy*OW;
    int IH = OH>>1, IW = OW>>1;
    int iz=oz>>1, iy=oy>>1, ix=ox>>1;
    int wt = ((1-(oz&1))*2 + (1-(oy&1)))*2 + (1-(ox&1));
    const float* xp = x + (size_t)((iz*IH+iy)*IW+ix)*CI;
    const float* wp = w + (size_t)wt*CI*CO + co;
    float acc = 0.f;
#pragma unroll 4
    for (int ci=0;ci<CI;++ci) acc = fmaf(xp[ci], wp[(size_t)ci*CO], acc);
    out[idx] = acc;
}

// ---------------- launch ----------------
extern "C" void kernel_launch(void* const* d_in, const int* in_sizes, int n_in,
                              void* d_out, int out_size, void* d_ws, size_t ws_size,
                              hipStream_t stream)
{
    const float* features = (const float*)d_in[0];
    const int*   coors    = (const int*)d_in[1];
    const int N = in_sizes[0] / 3;
    const float* w1  = (const float*)d_in[3];
    const float* w2  = (const float*)d_in[4];
    const float* w3  = (const float*)d_in[5];
    const float* w4  = (const float*)d_in[6];
    const float* w5  = (const float*)d_in[7];
    const float* w6  = (const float*)d_in[8];
    const float* w7  = (const float*)d_in[9];
    const float* w8  = (const float*)d_in[10];
    const float* w9  = (const float*)d_in[11];
    const float* w10 = (const float*)d_in[12];
    const float* w11 = (const float*)d_in[13];
    const float* w12 = (const float*)d_in[14];
    const float* w13 = (const float*)d_in[15];
    const float* w14 = (const float*)d_in[16];
    const float* w15 = (const float*)d_in[17];
    const float* w16 = (const float*)d_in[18];
    const float* w17 = (const float*)d_in[19];
    const float* w18 = (const float*)d_in[20];

    char* p = (char*)d_ws;
    auto alloc = [&](size_t bytes)->void* {
        void* r = (void*)p; p += (bytes + 255) & ~(size_t)255; return r;
    };
    int*   gridA = (int*)  alloc((size_t)NCELL*4);
    int*   grid2 = (int*)  alloc((size_t)NCELL*4);
    int*   partS = (int*)  alloc((size_t)512*4);
    int*   cellOf= (int*)  alloc((size_t)N*4);
    float* featS = (float*)alloc((size_t)N*4*4);
    float* sA0   = (float*)alloc((size_t)N*64*4);   // also conv5 partial region
    float* sA1   = (float*)alloc((size_t)N*64*4);
    float* xB0   = (float*)alloc((size_t)65536*96*4);
    float* xB1   = (float*)alloc((size_t)65536*96*4);
    float* m1    = (float*)alloc((size_t)65536*4);
    float* xC0   = (float*)alloc((size_t)8192*128*4);
    float* xC1   = (float*)alloc((size_t)8192*128*4);
    float* m2    = (float*)alloc((size_t)8192*4);
    float* xD0   = (float*)alloc((size_t)1024*160*4);
    float* xD1   = (float*)alloc((size_t)1024*160*4);
    float* m3    = (float*)alloc((size_t)1024*4);
    float* xE0   = (float*)alloc((size_t)128*192*4);
    float* xE1   = (float*)alloc((size_t)128*192*4);
    float* m4    = (float*)alloc((size_t)128*4);
    float* xF0   = (float*)alloc((size_t)16*224*4);
    float* xF1   = (float*)alloc((size_t)16*224*4);
    float* m5    = (float*)alloc((size_t)16*4);
    float* dT1   = (float*)alloc((size_t)128*128*4);
    if ((size_t)(p - (char*)d_ws) > ws_size) return;
    float* part  = sA0;   // conv5/dense partial scratch (after stage A consumed)

    // ---- grid + spatial sort
    hipMemsetAsync(gridA, 0xFF, (size_t)NCELL*4, stream);
    build_grid_k<<<(N+255)/256,256,0,stream>>>(coors, gridA, N);
    scan1_k<<<512,256,0,stream>>>(gridA, partS);
    scan2_k<<<1,512,0,stream>>>(partS);
    scan3_k<<<512,256,0,stream>>>(gridA, partS, features, grid2, cellOf, featS);

    // ---- stage A (sorted, XCD-swizzled): 1 vox/thread, co-tile 16, max blocks
    int gx1 = (N + 255) / 256;   // 1-vox site-blocks (586)
    subm_first_k<<<dim3(gx1,2),256,0,stream>>>(featS, grid2, cellOf, w1, sA0, N);
    subm1c_k<32,32><<<dim3(gx1,2),256,0,stream>>>(sA0, grid2, cellOf, w2, sA1, N);
    subm1c_k<32,64><<<dim3(gx1,4),256,0,stream>>>(sA1, grid2, cellOf, w3, sA0, N);
    subm1c_k<64,64><<<dim3(gx1,4),256,0,stream>>>(sA0, grid2, cellOf, w4, sA1, N);

    // ---- conv5 (reads sA1; partials in sA0: 2*16.8MB <= 38.4MB) -> xB0
    conv5s_k<64,64><<<dim3(128,2,2),256,0,stream>>>(sA1, grid2, w5, sA0, 14);
    reduce_k<<<(65536*64+255)/256,256,0,stream>>>(sA0, xB0, nullptr, 65536, 64, 2);
    mask_from_gridA_k<<<256,256,0,stream>>>(gridA, m1);

    // ---- stage B (64,64,16): LDS-tiled, all 27 taps in one pass, mask fused
    convB_tile_k<64,96><<<dim3(256,3),256,0,stream>>>(xB0, w6, m1, xB1);
    convB_tile_k<96,96><<<dim3(256,3),256,0,stream>>>(xB1, w7, m1, xB0);

    // ---- conv8: k2 s2 VALID (naturally masked), 2-vox G=8
    dense2v_k<96,96,2,2,0, 64,64,16, 32,32,8><<<dim3(16,3,8),256,0,stream>>>(xB0, w8, part, 1);
    reduce_k<<<(8192*96+255)/256,256,0,stream>>>(part, xC0, nullptr, 8192, 96, 8);
    mask_pool2_k<<<(8192+255)/256,256,0,stream>>>(m1, m2, 32,32,8);

    // ---- stage C (32,32,8), 2-vox G=9 (partials 9*4.2MB = 37.7MB <= 38.4)
    dense2v_k<96,128,3,1,1, 32,32,8, 32,32,8><<<dim3(16,4,9),256,0,stream>>>(xC0, w9, part, 3);
    reduce_k<<<(8192*128+255)/256,256,0,stream>>>(part, xC1, m2, 8192, 128, 9);
    dense2v_k<128,128,3,1,1, 32,32,8, 32,32,8><<<dim3(16,4,9),256,0,stream>>>(xC1, w10, part, 3);
    reduce_k<<<(8192*128+255)/256,256,0,stream>>>(part, xC0, m2, 8192, 128, 9);

    // ---- C -> D maxpool + m3
    mask_pool2_k<<<(1024+255)/256,256,0,stream>>>(m2, m3, 16,16,4);
    maxpool2_k<128><<<(1024*128+255)/256,256,0,stream>>>(xC0, m2, xD0, 16,16,4);

    // ---- stage D (16,16,4), 2-vox G=27
    dense2v_k<128,160,3,1,1, 16,16,4, 16,16,4><<<dim3(2,5,27),256,0,stream>>>(xD0, w11, part, 1);
    reduce_k<<<(1024*160+255)/256,256,0,stream>>>(part, xD1, m3, 1024, 160, 27);
    dense2v_k<160,160,3,1,1, 16,16,4, 16,16,4><<<dim3(2,5,27),256,0,stream>>>(xD1, w12, part, 1);
    reduce_k<<<(1024*160+255)/256,256,0,stream>>>(part, xD0, m3, 1024, 160, 27);

    // ---- D -> E maxpool + m4
    mask_pool2_k<<<1,256,0,stream>>>(m3, m4, 8,8,2);
    maxpool2_k<160><<<(128*160+255)/256,256,0,stream>>>(xD0, m3, xE0, 8,8,2);

    // ---- stage E (8,8,2): thread-per-(vox,tap,co) split
    conv_ks_k<160,192, 8,8,2><<<(128*27*192+255)/256,256,0,stream>>>(xE0, w13, part);
    reduce_k<<<(128*192+255)/256,256,0,stream>>>(part, xE1, m4, 128, 192, 27);
    conv_ks_k<192,192, 8,8,2><<<(128*27*192+255)/256,256,0,stream>>>(xE1, w14, part);
    reduce_k<<<(128*192+255)/256,256,0,stream>>>(part, xE0, m4, 128, 192, 27);

    // ---- E -> F maxpool + m5
    mask_pool2_k<<<1,256,0,stream>>>(m4, m5, 4,4,1);
    maxpool2_k<192><<<(16*192+255)/256,256,0,stream>>>(xE0, m4, xF0, 4,4,1);

    // ---- stage F (4,4,1)
    conv_ks_k<192,224, 4,4,1><<<(16*27*224+255)/256,256,0,stream>>>(xF0, w15, part);
    reduce_k<<<(16*224+255)/256,256,0,stream>>>(part, xF1, m5, 16, 224, 27);
    conv_ks_k<224,224, 4,4,1><<<(16*27*224+255)/256,256,0,stream>>>(xF1, w16, part);
    reduce_k<<<(16*224+255)/256,256,0,stream>>>(part, xF0, m5, 16, 224, 27);

    // ---- deconvs (taps flipped), masked by m4 then m3; final write = d_out
    deconv2x_k<224,128><<<(8*8*2*128+255)/256,256,0,stream>>>(xF0, w17, m4, dT1, 8,8,2);
    deconv2x_k<128,64><<<(16*16*4*64+255)/256,256,0,stream>>>(dT1, w18, m3, (float*)d_out, 16,16,4);
}

// Round 13
// 2513.190 us; speedup vs baseline: 1.9446x; 1.1273x over previous
//
#include <hip/hip_runtime.h>
#include <cstdint>
#include <cstddef>

// Stage-A dense grid dims: flat cell = (z<<12)|(y<<5)|x
#define AD 128
#define AH 128
#define AW 32
#define NCELL (AD*AH*AW)   // 524288

// XCD-contiguous block swizzle: blocks with equal (bid&7) — same XCD under
// round-robin dispatch — get CONTIGUOUS logical ranges. Perf-only remap.
__device__ __forceinline__ int xcd_swizzle(int bx, int nb) {
    int xcd = bx & 7, slot = bx >> 3;
    int base = nb >> 3, rem = nb & 7;
    return (xcd < rem) ? (xcd*(base+1) + slot) : (rem + xcd*base + slot);
}

// ---------------- setup: grid + spatial sort (occupancy scan) ----------------
__global__ void build_grid_k(const int* __restrict__ coors, int* __restrict__ grid, int N) {
    int i = blockIdx.x * 256 + threadIdx.x;
    if (i >= N) return;
    int z = coors[i*4+1], y = coors[i*4+2], x = coors[i*4+3];
    grid[(z*AH + y)*AW + x] = i;
}

__global__ __launch_bounds__(256) void scan1_k(const int* __restrict__ grid, int* __restrict__ partial) {
    __shared__ int sm[256];
    int tid = threadIdx.x;
    int base = blockIdx.x*1024 + tid*4;
    int c = 0;
#pragma unroll
    for (int k = 0; k < 4; ++k) c += (grid[base+k] >= 0) ? 1 : 0;
    sm[tid] = c; __syncthreads();
    for (int off = 128; off; off >>= 1) {
        if (tid < off) sm[tid] += sm[tid+off];
        __syncthreads();
    }
    if (tid == 0) partial[blockIdx.x] = sm[0];
}

__global__ __launch_bounds__(512) void scan2_k(int* __restrict__ partial) {
    __shared__ int sm[512];
    int tid = threadIdx.x;
    int own = partial[tid];
    sm[tid] = own; __syncthreads();
    for (int off = 1; off < 512; off <<= 1) {
        int v = (tid >= off) ? sm[tid-off] : 0;
        __syncthreads();
        sm[tid] += v;
        __syncthreads();
    }
    partial[tid] = sm[tid] - own;   // exclusive
}

__global__ __launch_bounds__(256) void scan3_k(const int* __restrict__ grid, const int* __restrict__ partial,
                                               const float* __restrict__ features,
                                               int* __restrict__ grid2, int* __restrict__ cellOf,
                                               float* __restrict__ featS) {
    __shared__ int sm[256];
    int tid = threadIdx.x;
    int base = blockIdx.x*1024 + tid*4;
    int olds[4]; int c = 0;
#pragma unroll
    for (int k = 0; k < 4; ++k) { olds[k] = grid[base+k]; c += (olds[k] >= 0) ? 1 : 0; }
    int own = c;
    sm[tid] = c; __syncthreads();
    for (int off = 1; off < 256; off <<= 1) {
        int v = (tid >= off) ? sm[tid-off] : 0;
        __syncthreads();
        sm[tid] += v;
        __syncthreads();
    }
    int j = partial[blockIdx.x] + sm[tid] - own;
#pragma unroll
    for (int k = 0; k < 4; ++k) {
        int cell = base + k, old = olds[k];
        if (old >= 0) {
            grid2[cell] = j; cellOf[j] = cell;
            featS[j*4+0] = features[old*3+0];
            featS[j*4+1] = features[old*3+1];
            featS[j*4+2] = features[old*3+2];
            featS[j*4+3] = 0.f;
            ++j;
        } else grid2[cell] = -1;
    }
}

// ---------------- first layer: CI=3 (stride 4), co-16 split ----------------
__global__ __launch_bounds__(256, 6)
void subm_first_k(const float* __restrict__ featS, const int* __restrict__ grid2,
                  const int* __restrict__ cellOf, const float* __restrict__ w,
                  float* __restrict__ out, int nsites)
{
    int j = blockIdx.x*256 + threadIdx.x;
    const int co0 = blockIdx.y*16;
    bool ok = j < nsites;
    int cell = ok ? cellOf[j] : 0;
    int z = cell >> 12, y = (cell >> 5) & 127, x = cell & 31;
    float acc[16];
#pragma unroll
    for (int n = 0; n < 16; ++n) acc[n] = 0.f;
    for (int t = 0; t < 27; ++t) {
        int nz = z + t/9 - 1, ny = y + (t/3)%3 - 1, nx = x + t%3 - 1;
        int s = -1;
        if (ok && nz>=0 && nz<AD && ny>=0 && ny<AH && nx>=0 && nx<AW)
            s = grid2[(nz<<12)|(ny<<5)|nx];
        float4 v = make_float4(0.f,0.f,0.f,0.f);
        if (s >= 0) v = ((const float4*)featS)[s];
        const float* wc = w + t*3*32 + co0;
        float av[3] = {v.x, v.y, v.z};
#pragma unroll
        for (int u = 0; u < 3; ++u)
#pragma unroll
            for (int n = 0; n < 16; ++n)
                acc[n] = fmaf(av[u], wc[u*32+n], acc[n]);
    }
    if (ok) {
        float4* op = (float4*)(out + (size_t)j*32 + co0);
#pragma unroll
        for (int q = 0; q < 4; ++q)
            op[q] = make_float4(acc[4*q], acc[4*q+1], acc[4*q+2], acc[4*q+3]);
    }
}

// ---------------- stage-A submanifold conv: 1 vox/thread, co-tile 16, max TLP ----------------
template<int CI, int CO>
__global__ __launch_bounds__(256, 6)
void subm1c_k(const float* __restrict__ in, const int* __restrict__ grid2,
              const int* __restrict__ cellOf, const float* __restrict__ w,
              float* __restrict__ out, int nsites)
{
    const int tid = threadIdx.x;
    const int sbx = xcd_swizzle(blockIdx.x, gridDim.x);
    const int j = sbx*256 + tid;
    const int co0 = blockIdx.y*16;
    const bool ok = j < nsites;
    int cell = ok ? cellOf[j] : 0;
    const int z = cell >> 12, y = (cell >> 5) & 127, x = cell & 31;
    float acc[16];
#pragma unroll
    for (int n = 0; n < 16; ++n) acc[n] = 0.f;

#pragma unroll 1
    for (int t = 0; t < 27; ++t) {
        int dz = t/9 - 1, dy = (t/3)%3 - 1, dx = t%3 - 1;
        int nz = z+dz, ny = y+dy, nx = x+dx;
        int s = -1;
        if (ok && nz>=0 && nz<AD && ny>=0 && ny<AH && nx>=0 && nx<AW)
            s = grid2[(nz<<12)|(ny<<5)|nx];
        for (int c0 = 0; c0 < CI; c0 += 16) {
            const float4* rp = (const float4*)(in + (size_t)(s < 0 ? 0 : s)*CI + c0);
            float4 a0 = make_float4(0.f,0.f,0.f,0.f), a1 = a0, a2 = a0, a3 = a0;
            if (s >= 0) { a0 = rp[0]; a1 = rp[1]; a2 = rp[2]; a3 = rp[3]; }
            float xv[16] = {a0.x,a0.y,a0.z,a0.w, a1.x,a1.y,a1.z,a1.w,
                            a2.x,a2.y,a2.z,a2.w, a3.x,a3.y,a3.z,a3.w};
            const float* wc = w + ((size_t)t*CI + c0)*CO + co0;   // wave-uniform -> s_load
#pragma unroll
            for (int u = 0; u < 16; ++u) {
                const float* wr = wc + u*CO;
#pragma unroll
                for (int n = 0; n < 16; ++n)
                    acc[n] = fmaf(xv[u], wr[n], acc[n]);
            }
        }
    }
    if (ok) {
        float4* op = (float4*)(out + (size_t)j*CO + co0);
#pragma unroll
        for (int q = 0; q < 4; ++q)
            op[q] = make_float4(acc[4*q], acc[4*q+1], acc[4*q+2], acc[4*q+3]);
    }
}

// ---------------- conv5: k3 s2 p1 sparse-in dense-out, 1 vox/thread, co-16, direct write ----------------
template<int CI, int CO>
__global__ __launch_bounds__(256, 6)
void conv5c_k(const float* __restrict__ in, const int* __restrict__ grid2,
              const float* __restrict__ w, float* __restrict__ out)
{
    const int tid = threadIdx.x;
    const int sbx = xcd_swizzle(blockIdx.x, gridDim.x);
    const int o = sbx*256 + tid;   // 65536 exact
    const int co0 = blockIdx.y*16;
    const int oz = o >> 10, oy = (o >> 4) & 63, ox = o & 15;
    float acc[16];
#pragma unroll
    for (int n = 0; n < 16; ++n) acc[n] = 0.f;

#pragma unroll 1
    for (int t = 0; t < 27; ++t) {
        int iz = 2*oz + t/9 - 1, iy = 2*oy + (t/3)%3 - 1, ix = 2*ox + t%3 - 1;
        int s = -1;
        if (iz>=0 && iz<AD && iy>=0 && iy<AH && ix>=0 && ix<AW)
            s = grid2[(iz<<12)|(iy<<5)|ix];
        for (int c0 = 0; c0 < CI; c0 += 16) {
            const float4* rp = (const float4*)(in + (size_t)(s < 0 ? 0 : s)*CI + c0);
            float4 a0 = make_float4(0.f,0.f,0.f,0.f), a1 = a0, a2 = a0, a3 = a0;
            if (s >= 0) { a0 = rp[0]; a1 = rp[1]; a2 = rp[2]; a3 = rp[3]; }
            float xv[16] = {a0.x,a0.y,a0.z,a0.w, a1.x,a1.y,a1.z,a1.w,
                            a2.x,a2.y,a2.z,a2.w, a3.x,a3.y,a3.z,a3.w};
            const float* wc = w + ((size_t)t*CI + c0)*CO + co0;
#pragma unroll
            for (int u = 0; u < 16; ++u) {
                const float* wr = wc + u*CO;
#pragma unroll
                for (int n = 0; n < 16; ++n)
                    acc[n] = fmaf(xv[u], wr[n], acc[n]);
            }
        }
    }
    float4* op = (float4*)(out + (size_t)o*CO + co0);
#pragma unroll
    for (int q = 0; q < 4; ++q)
        op[q] = make_float4(acc[4*q], acc[4*q+1], acc[4*q+2], acc[4*q+3]);
}

// ---------------- LDS-tiled dense conv k3 s1 p1, stage B (64,64,16) ----------------
// Chunk 8 channels (STR=12, 28.8 KB LDS -> 5 blocks/CU), co-tile 16 (grid.y=CO/16).
template<int CI, int CO>
__global__ __launch_bounds__(256, 5)
void convB_tile_k(const float* __restrict__ in, const float* __restrict__ w,
                  const float* __restrict__ mask, float* __restrict__ out)
{
    constexpr int NH = 600;          // 6*10*10 halo cells
    constexpr int STR = 12;          // 8 ch + 4 pad floats
    __shared__ float sf[NH*STR];     // 28.8 KB

    const int tid = threadIdx.x;
    const int bx = blockIdx.x;                 // 0..255
    const int tx_ = bx & 1, ty_ = (bx >> 1) & 7, tz_ = bx >> 4;
    const int z0 = tz_*4, y0 = ty_*8, x0 = tx_*8;
    const int lz = tid >> 6, ly = (tid >> 3) & 7, lx = tid & 7;
    const int co0 = blockIdx.y*16;
    const int o = ((z0+lz)*64 + (y0+ly))*16 + (x0+lx);

    float acc[16];
#pragma unroll
    for (int n = 0; n < 16; ++n) acc[n] = 0.f;

    for (int c0 = 0; c0 < CI; c0 += 8) {
        __syncthreads();
        for (int i = tid; i < NH*2; i += 256) {
            int cell = i >> 1, q = i & 1;
            int hz = cell / 100; int rr = cell - hz*100; int hy = rr / 10; int hx = rr - hy*10;
            int gz = z0 + hz - 1, gy = y0 + hy - 1, gx = x0 + hx - 1;
            float4 v = make_float4(0.f,0.f,0.f,0.f);
            if (gz>=0 && gz<64 && gy>=0 && gy<64 && gx>=0 && gx<16)
                v = *(const float4*)(in + (size_t)((gz*64+gy)*16+gx)*CI + c0 + q*4);
            *(float4*)(&sf[cell*STR + q*4]) = v;
        }
        __syncthreads();
#pragma unroll 1
        for (int t = 0; t < 27; ++t) {
            int hz = lz + t/9, hy = ly + (t/3)%3, hx = lx + t%3;
            const float4* fp = (const float4*)(&sf[((hz*10 + hy)*10 + hx)*STR]);
            float4 f0 = fp[0], f1 = fp[1];
            float xv[8] = {f0.x,f0.y,f0.z,f0.w, f1.x,f1.y,f1.z,f1.w};
            const float* wt = w + ((size_t)t*CI + c0)*CO + co0;  // wave-uniform -> s_load
#pragma unroll
            for (int u = 0; u < 8; ++u) {
                const float* wr = wt + u*CO;
#pragma unroll
                for (int n = 0; n < 16; ++n)
                    acc[n] = fmaf(xv[u], wr[n], acc[n]);
            }
        }
    }
    float mv = mask[o];
    float4* op = (float4*)(out + (size_t)o*CO + co0);
#pragma unroll
    for (int q = 0; q < 4; ++q)
        op[q] = make_float4(acc[4*q]*mv, acc[4*q+1]*mv, acc[4*q+2]*mv, acc[4*q+3]*mv);
}

// ---------------- 2-voxel tap core, NCO-wide co tile (dense stages) ----------------
template<int CI, int CO, int NCO>
__device__ __forceinline__ void tap_fma(const float* __restrict__ in, const float* __restrict__ wtap,
                                        int s0, int s1, float (&acc)[2][NCO])
{
    for (int c0 = 0; c0 < CI; c0 += 16) {
        const float4* r0 = (const float4*)(in + (size_t)(s0 < 0 ? 0 : s0)*CI + c0);
        const float4* r1 = (const float4*)(in + (size_t)(s1 < 0 ? 0 : s1)*CI + c0);
        float4 a0[4], a1[4];
#pragma unroll
        for (int q = 0; q < 4; ++q) {
            a0[q] = (s0 >= 0) ? r0[q] : make_float4(0.f,0.f,0.f,0.f);
            a1[q] = (s1 >= 0) ? r1[q] : make_float4(0.f,0.f,0.f,0.f);
        }
        const float* wc = wtap + c0*CO;
#pragma unroll
        for (int u = 0; u < 16; ++u) {
            float x0 = ((const float*)a0)[u];
            float x1 = ((const float*)a1)[u];
            const float* wr = wc + u*CO;   // wave-uniform -> s_load
#pragma unroll
            for (int n = 0; n < NCO; ++n) {
                float wv = wr[n];
                acc[0][n] = fmaf(x0, wv, acc[0][n]);
                acc[1][n] = fmaf(x1, wv, acc[1][n]);
            }
        }
    }
}

template<int CO, int NCO>
__device__ __forceinline__ void store2(float* __restrict__ out, int co0, int j0, int j1,
                                       bool ok0, bool ok1, float (&acc)[2][NCO])
{
    if (ok0) {
        float4* op = (float4*)(out + (size_t)j0*CO + co0);
#pragma unroll
        for (int q = 0; q < NCO/4; ++q)
            op[q] = make_float4(acc[0][4*q], acc[0][4*q+1], acc[0][4*q+2], acc[0][4*q+3]);
    }
    if (ok1) {
        float4* op = (float4*)(out + (size_t)j1*CO + co0);
#pragma unroll
        for (int q = 0; q < NCO/4; ++q)
            op[q] = make_float4(acc[1][4*q], acc[1][4*q+1], acc[1][4*q+2], acc[1][4*q+3]);
    }
}

// ---------------- dense conv, tap-split: 2 voxels/thread (conv8, stages C, D) ----------------
template<int CI, int CO, int K, int S, int PAD, int ID, int IH, int IW, int OD, int OH, int OW>
__global__ __launch_bounds__(256, 3)
void dense2v_k(const float* __restrict__ in, const float* __restrict__ w,
               float* __restrict__ part, int tg)
{
    constexpr int NT = K*K*K;
    constexpr int NV = OD*OH*OW;
    const int tid = threadIdx.x;
    const int o0 = blockIdx.x*512 + tid, o1 = o0 + 256;
    const int co0 = blockIdx.y*32;
    const int g = blockIdx.z;
    const int t0 = g*tg, t1 = (t0 + tg < NT) ? (t0 + tg) : NT;
    int oz0 = o0/(OH*OW), r0v = o0 - oz0*(OH*OW), oy0 = r0v/OW, ox0 = r0v - oy0*OW;
    int oz1 = o1/(OH*OW), r1v = o1 - oz1*(OH*OW), oy1 = r1v/OW, ox1 = r1v - oy1*OW;
    float acc[2][32];
#pragma unroll
    for (int v = 0; v < 2; ++v)
#pragma unroll
        for (int n = 0; n < 32; ++n) acc[v][n] = 0.f;

#pragma unroll 1
    for (int t = t0; t < t1; ++t) {
        int kz = t/(K*K), rr = t - kz*(K*K), ky = rr/K, kx = rr - ky*K;
        int iz0 = oz0*S + kz - PAD, iy0 = oy0*S + ky - PAD, ix0 = ox0*S + kx - PAD;
        int iz1 = oz1*S + kz - PAD, iy1 = oy1*S + ky - PAD, ix1 = ox1*S + kx - PAD;
        int s0 = -1, s1 = -1;
        if (iz0>=0 && iz0<ID && iy0>=0 && iy0<IH && ix0>=0 && ix0<IW)
            s0 = (iz0*IH + iy0)*IW + ix0;
        if (iz1>=0 && iz1<ID && iy1>=0 && iy1<IH && ix1>=0 && ix1<IW)
            s1 = (iz1*IH + iy1)*IW + ix1;
        tap_fma<CI,CO,32>(in, w + (size_t)t*CI*CO + co0, s0, s1, acc);
    }
    store2<CO,32>(part + (size_t)g*NV*CO, co0, o0, o1, true, true, acc);
}

// ---------------- reduce partials (+ optional mask) ----------------
__global__ __launch_bounds__(256)
void reduce_k(const float* __restrict__ part, float* __restrict__ out,
              const float* __restrict__ mask, int NV, int CO, int G)
{
    int e = blockIdx.x*256 + threadIdx.x;
    if (e >= NV*CO) return;
    float s = 0.f;
    for (int g = 0; g < G; ++g) s += part[(size_t)g*NV*CO + e];
    if (mask) s *= mask[e / CO];
    out[e] = s;
}

// ---------------- tiny-stage subm conv: thread = (voxel, tap, co), partial out ----------------
template<int CI, int CO, int D_, int H_, int W_>
__global__ __launch_bounds__(256)
void conv_ks_k(const float* __restrict__ in, const float* __restrict__ w,
               float* __restrict__ part)
{
    constexpr int NV = D_*H_*W_;
    int idx = blockIdx.x*256 + threadIdx.x;
    if (idx >= NV*27*CO) return;
    int co = idx % CO;
    int rest = idx / CO;
    int t = rest % 27;
    int vox = rest / 27;
    int z = vox/(H_*W_), rv = vox - z*(H_*W_), y = rv/W_, x = rv - y*W_;
    int iz = z + t/9 - 1, iy = y + (t/3)%3 - 1, ix = x + t%3 - 1;
    float a = 0.f;
    if (iz>=0 && iz<D_ && iy>=0 && iy<H_ && ix>=0 && ix<W_) {
        const float4* xp = (const float4*)(in + (size_t)((iz*H_+iy)*W_+ix)*CI);
        const float* wp = w + (size_t)t*CI*CO + co;
#pragma unroll 4
        for (int c4 = 0; c4 < CI/4; ++c4) {
            float4 xv = xp[c4];
            a = fmaf(xv.x, wp[(size_t)(4*c4+0)*CO], a);
            a = fmaf(xv.y, wp[(size_t)(4*c4+1)*CO], a);
            a = fmaf(xv.z, wp[(size_t)(4*c4+2)*CO], a);
            a = fmaf(xv.w, wp[(size_t)(4*c4+3)*CO], a);
        }
    }
    part[((size_t)t*NV + vox)*CO + co] = a;
}

// ---------------- masks / pools / deconv ----------------
__global__ void mask_from_gridA_k(const int* __restrict__ grid, float* __restrict__ m1) {
    int o = blockIdx.x*256 + threadIdx.x;
    if (o >= 64*64*16) return;
    int oz = o >> 10, r = o & 1023, oy = r >> 4, ox = r & 15;
    int any = 0;
    for (int kz=0;kz<3;++kz) for(int ky=0;ky<3;++ky) for(int kx=0;kx<3;++kx){
        int iz=2*oz+kz-1, iy=2*oy+ky-1, ix=2*ox+kx-1;
        if (iz>=0&&iz<AD&&iy>=0&&iy<AH&&ix>=0&&ix<AW)
            any |= (grid[(iz*AH+iy)*AW+ix] >= 0) ? 1 : 0;
    }
    m1[o] = any ? 1.f : 0.f;
}

__global__ void mask_pool2_k(const float* __restrict__ mi, float* __restrict__ mo,
                             int OD,int OH,int OW) {
    int o = blockIdx.x*256 + threadIdx.x;
    if (o >= OD*OH*OW) return;
    int oz = o/(OH*OW); int r = o - oz*(OH*OW); int oy = r/OW, ox = r - oy*OW;
    int IH = OH*2, IW = OW*2;
    int any = 0;
    for (int dz=0;dz<2;++dz)for(int dy=0;dy<2;++dy)for(int dx=0;dx<2;++dx){
        int ii = ((2*oz+dz)*IH + (2*oy+dy))*IW + (2*ox+dx);
        any |= (mi[ii] > 0.f) ? 1 : 0;
    }
    mo[o] = any ? 1.f : 0.f;
}

template<int C>
__global__ void maxpool2_k(const float* __restrict__ x, const float* __restrict__ m,
                           float* __restrict__ out, int OD,int OH,int OW) {
    int idx = blockIdx.x*256 + threadIdx.x;
    int total = OD*OH*OW*C;
    if (idx >= total) return;
    int o = idx / C, c = idx - o*C;
    int oz = o/(OH*OW); int r = o - oz*(OH*OW); int oy = r/OW, ox = r - oy*OW;
    int IH = OH*2, IW = OW*2;
    float best = -3.402823466e38f; int any = 0;
    for (int dz=0;dz<2;++dz)for(int dy=0;dy<2;++dy)for(int dx=0;dx<2;++dx){
        int ii = ((2*oz+dz)*IH + (2*oy+dy))*IW + (2*ox+dx);
        if (m[ii] > 0.f) { any = 1; best = fmaxf(best, x[(size_t)ii*C + c]); }
    }
    out[idx] = any ? best : 0.f;
}

// conv_transpose k=2 s=2 VALID, transpose_kernel=False: out[2i+d] = x[i] . w[1-d]
template<int CI, int CO>
__global__ void deconv2x_k(const float* __restrict__ x, const float* __restrict__ w,
                           const float* __restrict__ m, float* __restrict__ out,
                           int OD,int OH,int OW) {
    int idx = blockIdx.x*256 + threadIdx.x;
    int total = OD*OH*OW*CO;
    if (idx >= total) return;
    int o = idx / CO, co = idx - o*CO;
    if (!(m[o] > 0.f)) { out[idx] = 0.f; return; }
    int oz = o/(OH*OW); int r = o - oz*(OH*OW); int oy = r/OW, ox = r - oy*OW;
    int IH = OH>>1, IW = OW>>1;
    int iz=oz>>1, iy=oy>>1, ix=ox>>1;
    int wt = ((1-(oz&1))*2 + (1-(oy&1)))*2 + (1-(ox&1));
    const float* xp = x + (size_t)((iz*IH+iy)*IW+ix)*CI;
    const float* wp = w + (size_t)wt*CI*CO + co;
    float acc = 0.f;
#pragma unroll 4
    for (int ci=0;ci<CI;++ci) acc = fmaf(xp[ci], wp[(size_t)ci*CO], acc);
    out[idx] = acc;
}

// ---------------- launch ----------------
extern "C" void kernel_launch(void* const* d_in, const int* in_sizes, int n_in,
                              void* d_out, int out_size, void* d_ws, size_t ws_size,
                              hipStream_t stream)
{
    const float* features = (const float*)d_in[0];
    const int*   coors    = (const int*)d_in[1];
    const int N = in_sizes[0] / 3;
    const float* w1  = (const float*)d_in[3];
    const float* w2  = (const float*)d_in[4];
    const float* w3  = (const float*)d_in[5];
    const float* w4  = (const float*)d_in[6];
    const float* w5  = (const float*)d_in[7];
    const float* w6  = (const float*)d_in[8];
    const float* w7  = (const float*)d_in[9];
    const float* w8  = (const float*)d_in[10];
    const float* w9  = (const float*)d_in[11];
    const float* w10 = (const float*)d_in[12];
    const float* w11 = (const float*)d_in[13];
    const float* w12 = (const float*)d_in[14];
    const float* w13 = (const float*)d_in[15];
    const float* w14 = (const float*)d_in[16];
    const float* w15 = (const float*)d_in[17];
    const float* w16 = (const float*)d_in[18];
    const float* w17 = (const float*)d_in[19];
    const float* w18 = (const float*)d_in[20];

    char* p = (char*)d_ws;
    auto alloc = [&](size_t bytes)->void* {
        void* r = (void*)p; p += (bytes + 255) & ~(size_t)255; return r;
    };
    int*   gridA = (int*)  alloc((size_t)NCELL*4);
    int*   grid2 = (int*)  alloc((size_t)NCELL*4);
    int*   partS = (int*)  alloc((size_t)512*4);
    int*   cellOf= (int*)  alloc((size_t)N*4);
    float* featS = (float*)alloc((size_t)N*4*4);
    float* sA0   = (float*)alloc((size_t)N*64*4);   // also dense partial region
    float* sA1   = (float*)alloc((size_t)N*64*4);
    float* xB0   = (float*)alloc((size_t)65536*96*4);
    float* xB1   = (float*)alloc((size_t)65536*96*4);
    float* m1    = (float*)alloc((size_t)65536*4);
    float* xC0   = (float*)alloc((size_t)8192*128*4);
    float* xC1   = (float*)alloc((size_t)8192*128*4);
    float* m2    = (float*)alloc((size_t)8192*4);
    float* xD0   = (float*)alloc((size_t)1024*160*4);
    float* xD1   = (float*)alloc((size_t)1024*160*4);
    float* m3    = (float*)alloc((size_t)1024*4);
    float* xE0   = (float*)alloc((size_t)128*192*4);
    float* xE1   = (float*)alloc((size_t)128*192*4);
    float* m4    = (float*)alloc((size_t)128*4);
    float* xF0   = (float*)alloc((size_t)16*224*4);
    float* xF1   = (float*)alloc((size_t)16*224*4);
    float* m5    = (float*)alloc((size_t)16*4);
    float* dT1   = (float*)alloc((size_t)128*128*4);
    if ((size_t)(p - (char*)d_ws) > ws_size) return;
    float* part  = sA0;   // dense partial scratch (after stage A consumed)

    // ---- grid + spatial sort
    hipMemsetAsync(gridA, 0xFF, (size_t)NCELL*4, stream);
    build_grid_k<<<(N+255)/256,256,0,stream>>>(coors, gridA, N);
    scan1_k<<<512,256,0,stream>>>(gridA, partS);
    scan2_k<<<1,512,0,stream>>>(partS);
    scan3_k<<<512,256,0,stream>>>(gridA, partS, features, grid2, cellOf, featS);

    // ---- stage A (sorted, XCD-swizzled): 1 vox/thread, co-tile 16, max blocks
    int gx1 = (N + 255) / 256;   // 1-vox site-blocks (586)
    subm_first_k<<<dim3(gx1,2),256,0,stream>>>(featS, grid2, cellOf, w1, sA0, N);
    subm1c_k<32,32><<<dim3(gx1,2),256,0,stream>>>(sA0, grid2, cellOf, w2, sA1, N);
    subm1c_k<32,64><<<dim3(gx1,4),256,0,stream>>>(sA1, grid2, cellOf, w3, sA0, N);
    subm1c_k<64,64><<<dim3(gx1,4),256,0,stream>>>(sA0, grid2, cellOf, w4, sA1, N);

    // ---- conv5: 1-vox co-16 direct write (no partials) -> xB0
    conv5c_k<64,64><<<dim3(256,4),256,0,stream>>>(sA1, grid2, w5, xB0);
    mask_from_gridA_k<<<256,256,0,stream>>>(gridA, m1);

    // ---- stage B (64,64,16): LDS-tiled (chunk 8, 28.8KB), co-16, mask fused
    convB_tile_k<64,96><<<dim3(256,6),256,0,stream>>>(xB0, w6, m1, xB1);
    convB_tile_k<96,96><<<dim3(256,6),256,0,stream>>>(xB1, w7, m1, xB0);

    // ---- conv8: k2 s2 VALID (naturally masked), 2-vox G=8
    dense2v_k<96,96,2,2,0, 64,64,16, 32,32,8><<<dim3(16,3,8),256,0,stream>>>(xB0, w8, part, 1);
    reduce_k<<<(8192*96+255)/256,256,0,stream>>>(part, xC0, nullptr, 8192, 96, 8);
    mask_pool2_k<<<(8192+255)/256,256,0,stream>>>(m1, m2, 32,32,8);

    // ---- stage C (32,32,8), 2-vox G=9 (partials 9*4.2MB = 37.7MB <= 38.4)
    dense2v_k<96,128,3,1,1, 32,32,8, 32,32,8><<<dim3(16,4,9),256,0,stream>>>(xC0, w9, part, 3);
    reduce_k<<<(8192*128+255)/256,256,0,stream>>>(part, xC1, m2, 8192, 128, 9);
    dense2v_k<128,128,3,1,1, 32,32,8, 32,32,8><<<dim3(16,4,9),256,0,stream>>>(xC1, w10, part, 3);
    reduce_k<<<(8192*128+255)/256,256,0,stream>>>(part, xC0, m2, 8192, 128, 9);

    // ---- C -> D maxpool + m3
    mask_pool2_k<<<(1024+255)/256,256,0,stream>>>(m2, m3, 16,16,4);
    maxpool2_k<128><<<(1024*128+255)/256,256,0,stream>>>(xC0, m2, xD0, 16,16,4);

    // ---- stage D (16,16,4), 2-vox G=27
    dense2v_k<128,160,3,1,1, 16,16,4, 16,16,4><<<dim3(2,5,27),256,0,stream>>>(xD0, w11, part, 1);
    reduce_k<<<(1024*160+255)/256,256,0,stream>>>(part, xD1, m3, 1024, 160, 27);
    dense2v_k<160,160,3,1,1, 16,16,4, 16,16,4><<<dim3(2,5,27),256,0,stream>>>(xD1, w12, part, 1);
    reduce_k<<<(1024*160+255)/256,256,0,stream>>>(part, xD0, m3, 1024, 160, 27);

    // ---- D -> E maxpool + m4
    mask_pool2_k<<<1,256,0,stream>>>(m3, m4, 8,8,2);
    maxpool2_k<160><<<(128*160+255)/256,256,0,stream>>>(xD0, m3, xE0, 8,8,2);

    // ---- stage E (8,8,2): thread-per-(vox,tap,co) split
    conv_ks_k<160,192, 8,8,2><<<(128*27*192+255)/256,256,0,stream>>>(xE0, w13, part);
    reduce_k<<<(128*192+255)/256,256,0,stream>>>(part, xE1, m4, 128, 192, 27);
    conv_ks_k<192,192, 8,8,2><<<(128*27*192+255)/256,256,0,stream>>>(xE1, w14, part);
    reduce_k<<<(128*192+255)/256,256,0,stream>>>(part, xE0, m4, 128, 192, 27);

    // ---- E -> F maxpool + m5
    mask_pool2_k<<<1,256,0,stream>>>(m4, m5, 4,4,1);
    maxpool2_k<192><<<(16*192+255)/256,256,0,stream>>>(xE0, m4, xF0, 4,4,1);

    // ---- stage F (4,4,1)
    conv_ks_k<192,224, 4,4,1><<<(16*27*224+255)/256,256,0,stream>>>(xF0, w15, part);
    reduce_k<<<(16*224+255)/256,256,0,stream>>>(part, xF1, m5, 16, 224, 27);
    conv_ks_k<224,224, 4,4,1><<<(16*27*224+255)/256,256,0,stream>>>(xF1, w16, part);
    reduce_k<<<(16*224+255)/256,256,0,stream>>>(part, xF0, m5, 16, 224, 27);

    // ---- deconvs (taps flipped), masked by m4 then m3; final write = d_out
    deconv2x_k<224,128><<<(8*8*2*128+255)/256,256,0,stream>>>(xF0, w17, m4, dT1, 8,8,2);
    deconv2x_k<128,64><<<(16*16*4*64+255)/256,256,0,stream>>>(dT1, w18, m3, (float*)d_out, 16,16,4);
}